// Round 6
// baseline (255.722 us; speedup 1.0000x reference)
//
#include <hip/hip_runtime.h>
#include <hip/hip_bf16.h>
#include <cstdint>
#include <cstddef>

typedef __bf16 bf16_t;
typedef __attribute__((ext_vector_type(8))) __bf16 bf16x8;
typedef __attribute__((ext_vector_type(4))) __bf16 bf16x4;
typedef __attribute__((ext_vector_type(4))) float f32x4;

#define AS1 __attribute__((address_space(1)))
#define AS3 __attribute__((address_space(3)))

static constexpr int Bn = 2, Sn = 2048, En = 1024, Hn = 16, Dn = 64;

// ---------------------------------------------------------------- convert X
__global__ __launch_bounds__(256) void convert_f32_bf16(
    const float* __restrict__ in, bf16_t* __restrict__ out, int n) {
  int i = (blockIdx.x * 256 + threadIdx.x) * 4;
  if (i < n) {
    float4 v = *(const float4*)(in + i);
    bf16x4 o;
    o[0] = (bf16_t)v.x; o[1] = (bf16_t)v.y; o[2] = (bf16_t)v.z; o[3] = (bf16_t)v.w;
    *(bf16x4*)(out + i) = o;
  }
}

// ------------------------------------------- transpose fp32 [R][C] -> bf16 [C][R]
__global__ __launch_bounds__(256) void transpose_conv(
    const float* __restrict__ in, bf16_t* __restrict__ out, int R, int C) {
  __shared__ float tile[32][33];
  int bx = blockIdx.x * 32, by = blockIdx.y * 32;
  int tx = threadIdx.x & 31, ty = threadIdx.x >> 5;  // ty 0..7
#pragma unroll
  for (int i = 0; i < 32; i += 8)
    tile[ty + i][tx] = in[(size_t)(by + ty + i) * C + bx + tx];
  __syncthreads();
#pragma unroll
  for (int i = 0; i < 32; i += 8)
    out[(size_t)(bx + ty + i) * R + by + tx] = (bf16_t)tile[tx][ty + i];
}

// -------------------------------- V [bh][S][64] -> Vt [bh][64][S]  (bf16)
__global__ __launch_bounds__(256) void transpose_v(
    const bf16_t* __restrict__ V, bf16_t* __restrict__ Vt) {
  __shared__ ushort tile[64][65];
  int bh = blockIdx.y, s0 = blockIdx.x * 64;
  int t = threadIdx.x;
  const ushort* src = (const ushort*)(V + ((size_t)bh * Sn + s0) * 64);
#pragma unroll
  for (int p = 0; p < 4; ++p) {
    int s = p * 16 + (t >> 4);
    int c = (t & 15) * 4;
    ushort4 v = *(const ushort4*)(src + (size_t)s * 64 + c);
    tile[s][c] = v.x; tile[s][c + 1] = v.y; tile[s][c + 2] = v.z; tile[s][c + 3] = v.w;
  }
  __syncthreads();
  ushort* dst = (ushort*)(Vt + ((size_t)bh * 64) * Sn + s0);
#pragma unroll
  for (int p = 0; p < 4; ++p) {
    int d = p * 16 + (t >> 4);
    int c = (t & 15) * 4;  // s offset within tile
    ushort4 v;
    v.x = tile[c][d]; v.y = tile[c + 1][d]; v.z = tile[c + 2][d]; v.w = tile[c + 3][d];
    *(ushort4*)(dst + (size_t)d * Sn + c) = v;
  }
}

// ---------------------------------------------------------------- GEMM core
// C = A[M][K] · Bt[N][K]^T. 128x128 tile, BK=32, 256 threads (2x2 waves of
// 64x64). global_load_lds width-16 staging; chunk XOR-swizzle (rule #21):
// LDS[row][chunk] holds global chunk (chunk ^ (row&3)); read applies same XOR.
template <int K_>
__device__ __forceinline__ void gemm_core(
    const bf16_t* __restrict__ A, const bf16_t* __restrict__ Bt,
    f32x4 (&acc)[4][4], int& col0, int& row0) {
  __shared__ bf16_t As[2][128 * 32];
  __shared__ bf16_t Bs[2][128 * 32];
  const int tid = threadIdx.x, lane = tid & 63, wid = tid >> 6;
  const int wm = wid >> 1, wn = wid & 1;
  const int m0 = blockIdx.y * 128, n0 = blockIdx.x * 128;
  const int KT = K_ / 32;

  auto stage = [&](bf16_t* as, bf16_t* bs, int kt) {
    int csw = ((lane & 3) ^ ((lane >> 2) & 3)) * 8;
#pragma unroll
    for (int j = 0; j < 2; ++j) {
      int r0 = wid * 32 + j * 16;
      const bf16_t* ga = A + (size_t)(m0 + r0 + (lane >> 2)) * K_ + kt * 32 + csw;
      __builtin_amdgcn_global_load_lds((const AS1 void*)ga, (AS3 void*)(as + r0 * 32), 16, 0, 0);
      const bf16_t* gb = Bt + (size_t)(n0 + r0 + (lane >> 2)) * K_ + kt * 32 + csw;
      __builtin_amdgcn_global_load_lds((const AS1 void*)gb, (AS3 void*)(bs + r0 * 32), 16, 0, 0);
    }
  };
  auto compute = [&](const bf16_t* as, const bf16_t* bs) {
    bf16x8 af[4], bfr[4];
    uint32_t swz = (uint32_t)(((lane >> 4) ^ (lane & 3)) << 4);
#pragma unroll
    for (int mi = 0; mi < 4; ++mi) {
      uint32_t row = (uint32_t)(wm * 64 + mi * 16 + (lane & 15));
      af[mi] = *(const bf16x8*)((const char*)as + row * 64 + swz);
    }
#pragma unroll
    for (int ni = 0; ni < 4; ++ni) {
      uint32_t row = (uint32_t)(wn * 64 + ni * 16 + (lane & 15));
      bfr[ni] = *(const bf16x8*)((const char*)bs + row * 64 + swz);
    }
#pragma unroll
    for (int mi = 0; mi < 4; ++mi)
#pragma unroll
      for (int ni = 0; ni < 4; ++ni)
        acc[mi][ni] = __builtin_amdgcn_mfma_f32_16x16x32_bf16(af[mi], bfr[ni], acc[mi][ni], 0, 0, 0);
  };

  stage(As[0], Bs[0], 0);
  __syncthreads();
  int cur = 0;
  for (int kt = 0; kt < KT - 1; ++kt) {
    stage(As[cur ^ 1], Bs[cur ^ 1], kt + 1);
    compute(As[cur], Bs[cur]);
    __syncthreads();
    cur ^= 1;
  }
  compute(As[cur], Bs[cur]);
  col0 = n0 + wn * 64 + (lane & 15);
  row0 = m0 + wm * 64 + ((lane >> 4) << 2);
}

__global__ __launch_bounds__(256) void gemm_qkv(
    const bf16_t* __restrict__ A, const bf16_t* __restrict__ Bt,
    const float* __restrict__ bias, bf16_t* __restrict__ Qb,
    bf16_t* __restrict__ Kb, bf16_t* __restrict__ Vb) {
  f32x4 acc[4][4] = {};
  int col0, row0;
  gemm_core<1024>(A, Bt, acc, col0, row0);
#pragma unroll
  for (int ni = 0; ni < 4; ++ni) {
    int n = col0 + ni * 16;
    float bv = bias[n];
    int which = n >> 10, nn = n & 1023;
    int h = nn >> 6, dd = nn & 63;
    bf16_t* dst = which == 0 ? Qb : (which == 1 ? Kb : Vb);
    // Q: fold 1/sqrt(64) AND log2(e) (exp2-softmax) into the stored scale.
    float scl = which == 0 ? 0.125f * 1.44269504f : 1.0f;
#pragma unroll
    for (int mi = 0; mi < 4; ++mi)
#pragma unroll
      for (int i = 0; i < 4; ++i) {
        int m = row0 + mi * 16 + i;
        int b = m >> 11, s = m & 2047;
        float v = (acc[mi][ni][i] + bv) * scl;
        dst[(((size_t)b * Hn + h) * Sn + s) * 64 + dd] = (bf16_t)v;
      }
  }
}

__global__ __launch_bounds__(256) void gemm_out(
    const bf16_t* __restrict__ A, const bf16_t* __restrict__ Bt,
    const float* __restrict__ bias, float* __restrict__ out) {
  f32x4 acc[4][4] = {};
  int col0, row0;
  gemm_core<1024>(A, Bt, acc, col0, row0);
#pragma unroll
  for (int ni = 0; ni < 4; ++ni) {
    int n = col0 + ni * 16;
    float bv = bias[n];
#pragma unroll
    for (int mi = 0; mi < 4; ++mi)
#pragma unroll
      for (int i = 0; i < 4; ++i) {
        int m = row0 + mi * 16 + i;
        out[(size_t)m * En + n] = acc[mi][ni][i] + bv;
      }
  }
}

// -------------------------------------------------------- flash attention fwd
// grid (16, B*H), 512 threads = 8 waves. Wave-group 0 (waves 0-3) owns
// q_tile pr, group 1 owns q_tile pr+16; ONE shared K/V stream of tiles
// 0..pr+16 (group 0 skips compute for t > pr but co-stages). K/V double-
// buffered via global_load_lds w16, pre-swizzled global source. exp2-softmax
// (log2e folded into Q), defer-max (T13, thr 11.5 log2-units).
__global__ __launch_bounds__(512) void attn_fwd(
    const bf16_t* __restrict__ Qb, const bf16_t* __restrict__ Kb,
    const bf16_t* __restrict__ Vt, bf16_t* __restrict__ AO) {
  __shared__ bf16_t Ks[2][64 * 64];
  __shared__ bf16_t Vs[2][64 * 64];
  __shared__ bf16_t Ps[8][16 * 64];
  const int tid = threadIdx.x, lane = tid & 63, wid = tid >> 6;  // 0..7
  const int bh = blockIdx.y;
  const int pr = blockIdx.x;             // 0..15
  const int q_tile = pr + ((wid >> 2) << 4);  // grp0: pr, grp1: pr+16
  const int nt = pr + 17;                // shared stream length
  const int qb = q_tile * 64 + (wid & 3) * 16;

  // stage K rows (kv) / V rows (d) of kv-tile t: wave w covers 8 rows
  // w*8..w*8+7, one global_load_lds each (16B/lane), source chunk
  // pre-swizzled (cp -> cp ^ (row&7)) to match read-side XOR.
  const int rl = lane >> 3;     // row within wave's 8-row group (== r&7)
  const int cp = lane & 7;      // physical 16B chunk
  auto issueKV = [&](int buf, int t) {
    int r = wid * 8 + rl;
    int sc = cp ^ rl;           // source logical chunk
    const bf16_t* gk = Kb + (((size_t)bh * Sn + t * 64 + r) << 6) + (sc << 3);
    __builtin_amdgcn_global_load_lds((const AS1 void*)gk,
        (AS3 void*)(&Ks[buf][wid * 512]), 16, 0, 0);
    const bf16_t* gv = Vt + ((size_t)bh * 64 + r) * Sn + t * 64 + (sc << 3);
    __builtin_amdgcn_global_load_lds((const AS1 void*)gv,
        (AS3 void*)(&Vs[buf][wid * 512]), 16, 0, 0);
  };

  bf16x8 aq[2];
  {
    const bf16_t* qp = Qb + ((size_t)bh * Sn + qb + (lane & 15)) * 64 + ((lane >> 4) << 3);
    aq[0] = *(const bf16x8*)qp;
    aq[1] = *(const bf16x8*)(qp + 32);
  }
  f32x4 O[4] = {};
  float m_run[4], l_run[4];
#pragma unroll
  for (int i = 0; i < 4; ++i) { m_run[i] = -1e30f; l_run[i] = 0.f; }

  issueKV(0, 0);
  for (int t = 0; t < nt; ++t) {
    const int buf = t & 1;
    asm volatile("s_waitcnt vmcnt(0)" ::: "memory");
    __syncthreads();
    if (t + 1 < nt) issueKV(buf ^ 1, t + 1);
    if (t <= q_tile) {  // wave-uniform: group 0 idles for t > pr
      const char* ksb = (const char*)Ks[buf];
      const char* vsb = (const char*)Vs[buf];
      // QK^T : S[16 q][64 kv]  (scores already in log2 units)
      f32x4 sc[4];
#pragma unroll
      for (int ni = 0; ni < 4; ++ni) {
        int kvr = ni * 16 + (lane & 15);
        uint32_t o0 = (uint32_t)(kvr * 128 + ((lane >> 4) << 4)) ^ (uint32_t)((kvr & 7) << 4);
        uint32_t o1 = (uint32_t)(kvr * 128 + 64 + ((lane >> 4) << 4)) ^ (uint32_t)((kvr & 7) << 4);
        bf16x8 b0 = *(const bf16x8*)(ksb + o0);
        bf16x8 b1 = *(const bf16x8*)(ksb + o1);
        f32x4 z = {};
        z = __builtin_amdgcn_mfma_f32_16x16x32_bf16(aq[0], b0, z, 0, 0, 0);
        sc[ni] = __builtin_amdgcn_mfma_f32_16x16x32_bf16(aq[1], b1, z, 0, 0, 0);
      }
      if (t == q_tile) {  // diagonal tile: causal mask
#pragma unroll
        for (int ni = 0; ni < 4; ++ni) {
          int kv = t * 64 + ni * 16 + (lane & 15);
#pragma unroll
          for (int i = 0; i < 4; ++i) {
            int q = qb + ((lane >> 4) << 2) + i;
            if (kv > q) sc[ni][i] = -1e30f;
          }
        }
      }
      // online softmax (row i lives at q = qb + (lane>>4)*4 + i)
      float mt[4];
#pragma unroll
      for (int i = 0; i < 4; ++i) {
        float v = fmaxf(fmaxf(sc[0][i], sc[1][i]), fmaxf(sc[2][i], sc[3][i]));
        v = fmaxf(v, __shfl_xor(v, 1));
        v = fmaxf(v, __shfl_xor(v, 2));
        v = fmaxf(v, __shfl_xor(v, 4));
        v = fmaxf(v, __shfl_xor(v, 8));
        mt[i] = v;
      }
      // defer-max: only rescale when some row grew by > 11.5 (log2 units)
      int ok = (mt[0] <= m_run[0] + 11.5f) && (mt[1] <= m_run[1] + 11.5f) &&
               (mt[2] <= m_run[2] + 11.5f) && (mt[3] <= m_run[3] + 11.5f);
      if (!__all(ok)) {
#pragma unroll
        for (int i = 0; i < 4; ++i) {
          float mn = fmaxf(m_run[i], mt[i]);
          float s = __builtin_exp2f(m_run[i] - mn);
          m_run[i] = mn;
          l_run[i] *= s;
#pragma unroll
          for (int n2 = 0; n2 < 4; ++n2) O[n2][i] *= s;
        }
      }
      float rs[4] = {0.f, 0.f, 0.f, 0.f};
      char* pw = (char*)Ps[wid];
#pragma unroll
      for (int ni = 0; ni < 4; ++ni)
#pragma unroll
        for (int i = 0; i < 4; ++i) {
          float p = __builtin_exp2f(sc[ni][i] - m_run[i]);
          rs[i] += p;
          int r = ((lane >> 4) << 2) + i;
          uint32_t off = (uint32_t)(r * 128 + (ni * 16 + (lane & 15)) * 2) ^ (uint32_t)((r & 7) << 4);
          *(bf16_t*)(pw + off) = (bf16_t)p;
        }
#pragma unroll
      for (int i = 0; i < 4; ++i) {
        float v = rs[i];
        v += __shfl_xor(v, 1);
        v += __shfl_xor(v, 2);
        v += __shfl_xor(v, 4);
        v += __shfl_xor(v, 8);
        l_run[i] += v;
      }
      asm volatile("s_waitcnt lgkmcnt(0)" ::: "memory");
      __builtin_amdgcn_sched_barrier(0);
      // PV : O += P[16 q][64 kv] x V[64 kv][64 d]
      bf16x8 pa[2];
      {
        int r = lane & 15;
        uint32_t o0 = (uint32_t)(r * 128 + ((lane >> 4) << 4)) ^ (uint32_t)((r & 7) << 4);
        uint32_t o1 = (uint32_t)(r * 128 + 64 + ((lane >> 4) << 4)) ^ (uint32_t)((r & 7) << 4);
        pa[0] = *(const bf16x8*)((const char*)pw + o0);
        pa[1] = *(const bf16x8*)((const char*)pw + o1);
      }
#pragma unroll
      for (int n2 = 0; n2 < 4; ++n2) {
        int dr = n2 * 16 + (lane & 15);
        uint32_t o0 = (uint32_t)(dr * 128 + ((lane >> 4) << 4)) ^ (uint32_t)((dr & 7) << 4);
        uint32_t o1 = (uint32_t)(dr * 128 + 64 + ((lane >> 4) << 4)) ^ (uint32_t)((dr & 7) << 4);
        bf16x8 v0 = *(const bf16x8*)(vsb + o0);
        bf16x8 v1 = *(const bf16x8*)(vsb + o1);
        O[n2] = __builtin_amdgcn_mfma_f32_16x16x32_bf16(pa[0], v0, O[n2], 0, 0, 0);
        O[n2] = __builtin_amdgcn_mfma_f32_16x16x32_bf16(pa[1], v1, O[n2], 0, 0, 0);
      }
    }
  }
  // epilogue: AO[b][s][h*64+d] bf16
  int b = bh >> 4, h = bh & 15;
#pragma unroll
  for (int i = 0; i < 4; ++i) {
    float inv = 1.0f / l_run[i];
    int q = qb + ((lane >> 4) << 2) + i;
#pragma unroll
    for (int n2 = 0; n2 < 4; ++n2) {
      int d = n2 * 16 + (lane & 15);
      AO[((size_t)b * Sn + q) * En + h * 64 + d] = (bf16_t)(O[n2][i] * inv);
    }
  }
}

// ---------------------------------------------------------------- launch
extern "C" void kernel_launch(void* const* d_in, const int* in_sizes, int n_in,
                              void* d_out, int out_size, void* d_ws, size_t ws_size,
                              hipStream_t stream) {
  const float* X     = (const float*)d_in[0];
  // d_in[1] = mask (causal; applied analytically)
  const float* W_qkv = (const float*)d_in[2];
  const float* b_qkv = (const float*)d_in[3];
  const float* W_o   = (const float*)d_in[4];
  const float* b_o   = (const float*)d_in[5];
  float* out = (float*)d_out;

  char* ws = (char*)d_ws;
  bf16_t* Xb  = (bf16_t*)(ws);
  bf16_t* WqT = (bf16_t*)(ws + 8388608);
  bf16_t* WoT = (bf16_t*)(ws + 14680064);
  bf16_t* Qb  = (bf16_t*)(ws + 16777216);
  bf16_t* Kb  = (bf16_t*)(ws + 25165824);
  bf16_t* Vb  = (bf16_t*)(ws + 33554432);
  bf16_t* Vt  = (bf16_t*)(ws + 41943040);
  bf16_t* AO  = (bf16_t*)(ws + 50331648);

  convert_f32_bf16<<<4096, 256, 0, stream>>>(X, Xb, Bn * Sn * En);
  transpose_conv<<<dim3(96, 32), 256, 0, stream>>>(W_qkv, WqT, 1024, 3072);
  transpose_conv<<<dim3(32, 32), 256, 0, stream>>>(W_o, WoT, 1024, 1024);
  gemm_qkv<<<dim3(24, 32), 256, 0, stream>>>(Xb, WqT, b_qkv, Qb, Kb, Vb);
  transpose_v<<<dim3(32, 32), 256, 0, stream>>>(Vb, Vt);
  attn_fwd<<<dim3(16, 32), 512, 0, stream>>>(Qb, Kb, Vt, AO);
  gemm_out<<<dim3(8, 32), 256, 0, stream>>>(AO, WoT, b_o, out);
}

// Round 7
// 243.720 us; speedup vs baseline: 1.0492x; 1.0492x over previous
//
#include <hip/hip_runtime.h>
#include <hip/hip_bf16.h>
#include <cstdint>
#include <cstddef>

typedef __bf16 bf16_t;
typedef __attribute__((ext_vector_type(8))) __bf16 bf16x8;
typedef __attribute__((ext_vector_type(4))) __bf16 bf16x4;
typedef __attribute__((ext_vector_type(4))) float f32x4;

#define AS1 __attribute__((address_space(1)))
#define AS3 __attribute__((address_space(3)))

static constexpr int Bn = 2, Sn = 2048, En = 1024, Hn = 16, Dn = 64;

// ---------------------------------------------------------------- convert X
__global__ __launch_bounds__(256) void convert_f32_bf16(
    const float* __restrict__ in, bf16_t* __restrict__ out, int n) {
  int i = (blockIdx.x * 256 + threadIdx.x) * 4;
  if (i < n) {
    float4 v = *(const float4*)(in + i);
    bf16x4 o;
    o[0] = (bf16_t)v.x; o[1] = (bf16_t)v.y; o[2] = (bf16_t)v.z; o[3] = (bf16_t)v.w;
    *(bf16x4*)(out + i) = o;
  }
}

// ------------------------------------------- transpose fp32 [R][C] -> bf16 [C][R]
__global__ __launch_bounds__(256) void transpose_conv(
    const float* __restrict__ in, bf16_t* __restrict__ out, int R, int C) {
  __shared__ float tile[32][33];
  int bx = blockIdx.x * 32, by = blockIdx.y * 32;
  int tx = threadIdx.x & 31, ty = threadIdx.x >> 5;  // ty 0..7
#pragma unroll
  for (int i = 0; i < 32; i += 8)
    tile[ty + i][tx] = in[(size_t)(by + ty + i) * C + bx + tx];
  __syncthreads();
#pragma unroll
  for (int i = 0; i < 32; i += 8)
    out[(size_t)(bx + ty + i) * R + by + tx] = (bf16_t)tile[tx][ty + i];
}

// -------------------------------- V [bh][S][64] -> Vt [bh][64][S]  (bf16)
__global__ __launch_bounds__(256) void transpose_v(
    const bf16_t* __restrict__ V, bf16_t* __restrict__ Vt) {
  __shared__ ushort tile[64][65];
  int bh = blockIdx.y, s0 = blockIdx.x * 64;
  int t = threadIdx.x;
  const ushort* src = (const ushort*)(V + ((size_t)bh * Sn + s0) * 64);
#pragma unroll
  for (int p = 0; p < 4; ++p) {
    int s = p * 16 + (t >> 4);
    int c = (t & 15) * 4;
    ushort4 v = *(const ushort4*)(src + (size_t)s * 64 + c);
    tile[s][c] = v.x; tile[s][c + 1] = v.y; tile[s][c + 2] = v.z; tile[s][c + 3] = v.w;
  }
  __syncthreads();
  ushort* dst = (ushort*)(Vt + ((size_t)bh * 64) * Sn + s0);
#pragma unroll
  for (int p = 0; p < 4; ++p) {
    int d = p * 16 + (t >> 4);
    int c = (t & 15) * 4;  // s offset within tile
    ushort4 v;
    v.x = tile[c][d]; v.y = tile[c + 1][d]; v.z = tile[c + 2][d]; v.w = tile[c + 3][d];
    *(ushort4*)(dst + (size_t)d * Sn + c) = v;
  }
}

// ---------------------------------------------------------------- GEMM core
// C = A[M][K] · Bt[N][K]^T. 128x128 tile, BK=32, 256 threads (2x2 waves of
// 64x64). global_load_lds width-16 staging; chunk XOR-swizzle (rule #21).
template <int K_>
__device__ __forceinline__ void gemm_core(
    const bf16_t* __restrict__ A, const bf16_t* __restrict__ Bt,
    f32x4 (&acc)[4][4], int& col0, int& row0) {
  __shared__ bf16_t As[2][128 * 32];
  __shared__ bf16_t Bs[2][128 * 32];
  const int tid = threadIdx.x, lane = tid & 63, wid = tid >> 6;
  const int wm = wid >> 1, wn = wid & 1;
  const int m0 = blockIdx.y * 128, n0 = blockIdx.x * 128;
  const int KT = K_ / 32;

  auto stage = [&](bf16_t* as, bf16_t* bs, int kt) {
    int csw = ((lane & 3) ^ ((lane >> 2) & 3)) * 8;
#pragma unroll
    for (int j = 0; j < 2; ++j) {
      int r0 = wid * 32 + j * 16;
      const bf16_t* ga = A + (size_t)(m0 + r0 + (lane >> 2)) * K_ + kt * 32 + csw;
      __builtin_amdgcn_global_load_lds((const AS1 void*)ga, (AS3 void*)(as + r0 * 32), 16, 0, 0);
      const bf16_t* gb = Bt + (size_t)(n0 + r0 + (lane >> 2)) * K_ + kt * 32 + csw;
      __builtin_amdgcn_global_load_lds((const AS1 void*)gb, (AS3 void*)(bs + r0 * 32), 16, 0, 0);
    }
  };
  auto compute = [&](const bf16_t* as, const bf16_t* bs) {
    bf16x8 af[4], bfr[4];
    uint32_t swz = (uint32_t)(((lane >> 4) ^ (lane & 3)) << 4);
#pragma unroll
    for (int mi = 0; mi < 4; ++mi) {
      uint32_t row = (uint32_t)(wm * 64 + mi * 16 + (lane & 15));
      af[mi] = *(const bf16x8*)((const char*)as + row * 64 + swz);
    }
#pragma unroll
    for (int ni = 0; ni < 4; ++ni) {
      uint32_t row = (uint32_t)(wn * 64 + ni * 16 + (lane & 15));
      bfr[ni] = *(const bf16x8*)((const char*)bs + row * 64 + swz);
    }
#pragma unroll
    for (int mi = 0; mi < 4; ++mi)
#pragma unroll
      for (int ni = 0; ni < 4; ++ni)
        acc[mi][ni] = __builtin_amdgcn_mfma_f32_16x16x32_bf16(af[mi], bfr[ni], acc[mi][ni], 0, 0, 0);
  };

  stage(As[0], Bs[0], 0);
  __syncthreads();
  int cur = 0;
  for (int kt = 0; kt < KT - 1; ++kt) {
    stage(As[cur ^ 1], Bs[cur ^ 1], kt + 1);
    compute(As[cur], Bs[cur]);
    __syncthreads();
    cur ^= 1;
  }
  compute(As[cur], Bs[cur]);
  col0 = n0 + wn * 64 + (lane & 15);
  row0 = m0 + wm * 64 + ((lane >> 4) << 2);
}

__global__ __launch_bounds__(256) void gemm_qkv(
    const bf16_t* __restrict__ A, const bf16_t* __restrict__ Bt,
    const float* __restrict__ bias, bf16_t* __restrict__ Qb,
    bf16_t* __restrict__ Kb, bf16_t* __restrict__ Vb) {
  f32x4 acc[4][4] = {};
  int col0, row0;
  gemm_core<1024>(A, Bt, acc, col0, row0);
#pragma unroll
  for (int ni = 0; ni < 4; ++ni) {
    int n = col0 + ni * 16;
    float bv = bias[n];
    int which = n >> 10, nn = n & 1023;
    int h = nn >> 6, dd = nn & 63;
    bf16_t* dst = which == 0 ? Qb : (which == 1 ? Kb : Vb);
    // Q: fold 1/sqrt(64) AND log2(e) (exp2-softmax) into the stored scale.
    float scl = which == 0 ? 0.125f * 1.44269504f : 1.0f;
#pragma unroll
    for (int mi = 0; mi < 4; ++mi)
#pragma unroll
      for (int i = 0; i < 4; ++i) {
        int m = row0 + mi * 16 + i;
        int b = m >> 11, s = m & 2047;
        float v = (acc[mi][ni][i] + bv) * scl;
        dst[(((size_t)b * Hn + h) * Sn + s) * 64 + dd] = (bf16_t)v;
      }
  }
}

__global__ __launch_bounds__(256) void gemm_out(
    const bf16_t* __restrict__ A, const bf16_t* __restrict__ Bt,
    const float* __restrict__ bias, float* __restrict__ out) {
  f32x4 acc[4][4] = {};
  int col0, row0;
  gemm_core<1024>(A, Bt, acc, col0, row0);
#pragma unroll
  for (int ni = 0; ni < 4; ++ni) {
    int n = col0 + ni * 16;
    float bv = bias[n];
#pragma unroll
    for (int mi = 0; mi < 4; ++mi)
#pragma unroll
      for (int i = 0; i < 4; ++i) {
        int m = row0 + mi * 16 + i;
        out[(size_t)m * En + n] = acc[mi][ni][i] + bv;
      }
  }
}

// -------------------------------------------------------- flash attention fwd
// grid (16, B*H), 256 threads (4 waves x 16 q-rows). Causal pairing: block pr
// handles q_tiles {pr, 31-pr} = 33 kv-tile iterations, flattened into ONE
// global stream with 3-buffer LDS rotation and 2-tile-deep prefetch:
//   top of tile u: s_waitcnt vmcnt(4) (tile u done, u+1 in flight) -> barrier
//   -> issue tile u+2 into buf (u+2)%3. vmcnt(0) only on the last tile (T4).
// K/V staged via global_load_lds w16 with pre-swizzled global source.
// exp2-softmax (log2e folded into Q), defer-max (T13, thr 11.5 log2-units),
// setprio around MFMA clusters (T5).
__global__ __launch_bounds__(256) void attn_fwd(
    const bf16_t* __restrict__ Qb, const bf16_t* __restrict__ Kb,
    const bf16_t* __restrict__ Vt, bf16_t* __restrict__ AO) {
  __shared__ bf16_t Ks[3][64 * 64];
  __shared__ bf16_t Vs[3][64 * 64];
  __shared__ bf16_t Ps[4][16 * 64];
  const int tid = threadIdx.x, lane = tid & 63, wid = tid >> 6;
  const int bh = blockIdx.y;
  const int pr = blockIdx.x;      // pair index 0..15
  const int nt0 = pr + 1;         // length of segment 0
  const int NT = 33;              // total stream length

  const int rl = lane >> 3;       // row within 8-row group
  const int cp = lane & 7;        // physical 16B chunk
  auto issueKV = [&](int buf, int t) {
#pragma unroll
    for (int j = 0; j < 2; ++j) {
      int r = wid * 16 + j * 8 + rl;
      int sc = cp ^ rl;           // source logical chunk (pre-swizzle, r&7==rl)
      const bf16_t* gk = Kb + (((size_t)bh * Sn + t * 64 + r) << 6) + (sc << 3);
      __builtin_amdgcn_global_load_lds((const AS1 void*)gk,
          (AS3 void*)(&Ks[buf][wid * 1024 + j * 512]), 16, 0, 0);
      const bf16_t* gv = Vt + ((size_t)bh * 64 + r) * Sn + t * 64 + (sc << 3);
      __builtin_amdgcn_global_load_lds((const AS1 void*)gv,
          (AS3 void*)(&Vs[buf][wid * 1024 + j * 512]), 16, 0, 0);
    }
  };
  auto issue_u = [&](int g) { issueKV(g % 3, g < nt0 ? g : g - nt0); };

  issue_u(0);
  issue_u(1);
  int pf = 2;  // next global stream index to issue

  for (int seg = 0; seg < 2; ++seg) {
    const int q_tile = seg ? 31 - pr : pr;
    const int ntseg = q_tile + 1;
    const int qb = q_tile * 64 + wid * 16;

    bf16x8 aq[2];
    {
      const bf16_t* qp = Qb + ((size_t)bh * Sn + qb + (lane & 15)) * 64 + ((lane >> 4) << 3);
      aq[0] = *(const bf16x8*)qp;
      aq[1] = *(const bf16x8*)(qp + 32);
    }
    f32x4 O[4] = {};
    float m_run[4], l_run[4];
#pragma unroll
    for (int i = 0; i < 4; ++i) { m_run[i] = -1e30f; l_run[i] = 0.f; }

    for (int tloc = 0; tloc < ntseg; ++tloc) {
      const int u = seg ? nt0 + tloc : tloc;
      if (pf > u + 1) { asm volatile("s_waitcnt vmcnt(4)" ::: "memory"); }
      else            { asm volatile("s_waitcnt vmcnt(0)" ::: "memory"); }
      __syncthreads();
      if (pf < NT) { issue_u(pf); ++pf; }
      const char* ksb = (const char*)Ks[u % 3];
      const char* vsb = (const char*)Vs[u % 3];
      // QK^T : S[16 q][64 kv]  (scores already in log2 units)
      f32x4 sc[4];
      __builtin_amdgcn_s_setprio(1);
#pragma unroll
      for (int ni = 0; ni < 4; ++ni) {
        int kvr = ni * 16 + (lane & 15);
        uint32_t o0 = (uint32_t)(kvr * 128 + ((lane >> 4) << 4)) ^ (uint32_t)((kvr & 7) << 4);
        uint32_t o1 = (uint32_t)(kvr * 128 + 64 + ((lane >> 4) << 4)) ^ (uint32_t)((kvr & 7) << 4);
        bf16x8 b0 = *(const bf16x8*)(ksb + o0);
        bf16x8 b1 = *(const bf16x8*)(ksb + o1);
        f32x4 z = {};
        z = __builtin_amdgcn_mfma_f32_16x16x32_bf16(aq[0], b0, z, 0, 0, 0);
        sc[ni] = __builtin_amdgcn_mfma_f32_16x16x32_bf16(aq[1], b1, z, 0, 0, 0);
      }
      __builtin_amdgcn_s_setprio(0);
      if (tloc == ntseg - 1) {  // diagonal tile: causal mask
#pragma unroll
        for (int ni = 0; ni < 4; ++ni) {
          int kv = tloc * 64 + ni * 16 + (lane & 15);
#pragma unroll
          for (int i = 0; i < 4; ++i) {
            int q = qb + ((lane >> 4) << 2) + i;
            if (kv > q) sc[ni][i] = -1e30f;
          }
        }
      }
      // online softmax (row i lives at q = qb + (lane>>4)*4 + i)
      float mt[4];
#pragma unroll
      for (int i = 0; i < 4; ++i) {
        float v = fmaxf(fmaxf(sc[0][i], sc[1][i]), fmaxf(sc[2][i], sc[3][i]));
        v = fmaxf(v, __shfl_xor(v, 1));
        v = fmaxf(v, __shfl_xor(v, 2));
        v = fmaxf(v, __shfl_xor(v, 4));
        v = fmaxf(v, __shfl_xor(v, 8));
        mt[i] = v;
      }
      // defer-max: only rescale when some row grew by > 11.5 (log2 units)
      int ok = (mt[0] <= m_run[0] + 11.5f) && (mt[1] <= m_run[1] + 11.5f) &&
               (mt[2] <= m_run[2] + 11.5f) && (mt[3] <= m_run[3] + 11.5f);
      if (!__all(ok)) {
#pragma unroll
        for (int i = 0; i < 4; ++i) {
          float mn = fmaxf(m_run[i], mt[i]);
          float s = __builtin_exp2f(m_run[i] - mn);
          m_run[i] = mn;
          l_run[i] *= s;
#pragma unroll
          for (int n2 = 0; n2 < 4; ++n2) O[n2][i] *= s;
        }
      }
      float rs[4] = {0.f, 0.f, 0.f, 0.f};
      char* pw = (char*)Ps[wid];
#pragma unroll
      for (int ni = 0; ni < 4; ++ni)
#pragma unroll
        for (int i = 0; i < 4; ++i) {
          float p = __builtin_exp2f(sc[ni][i] - m_run[i]);
          rs[i] += p;
          int r = ((lane >> 4) << 2) + i;
          uint32_t off = (uint32_t)(r * 128 + (ni * 16 + (lane & 15)) * 2) ^ (uint32_t)((r & 7) << 4);
          *(bf16_t*)(pw + off) = (bf16_t)p;
        }
#pragma unroll
      for (int i = 0; i < 4; ++i) {
        float v = rs[i];
        v += __shfl_xor(v, 1);
        v += __shfl_xor(v, 2);
        v += __shfl_xor(v, 4);
        v += __shfl_xor(v, 8);
        l_run[i] += v;
      }
      asm volatile("s_waitcnt lgkmcnt(0)" ::: "memory");
      __builtin_amdgcn_sched_barrier(0);
      // PV : O += P[16 q][64 kv] x V[64 kv][64 d]
      bf16x8 pa[2];
      {
        int r = lane & 15;
        uint32_t o0 = (uint32_t)(r * 128 + ((lane >> 4) << 4)) ^ (uint32_t)((r & 7) << 4);
        uint32_t o1 = (uint32_t)(r * 128 + 64 + ((lane >> 4) << 4)) ^ (uint32_t)((r & 7) << 4);
        pa[0] = *(const bf16x8*)((const char*)pw + o0);
        pa[1] = *(const bf16x8*)((const char*)pw + o1);
      }
      __builtin_amdgcn_s_setprio(1);
#pragma unroll
      for (int n2 = 0; n2 < 4; ++n2) {
        int dr = n2 * 16 + (lane & 15);
        uint32_t o0 = (uint32_t)(dr * 128 + ((lane >> 4) << 4)) ^ (uint32_t)((dr & 7) << 4);
        uint32_t o1 = (uint32_t)(dr * 128 + 64 + ((lane >> 4) << 4)) ^ (uint32_t)((dr & 7) << 4);
        bf16x8 v0 = *(const bf16x8*)(vsb + o0);
        bf16x8 v1 = *(const bf16x8*)(vsb + o1);
        O[n2] = __builtin_amdgcn_mfma_f32_16x16x32_bf16(pa[0], v0, O[n2], 0, 0, 0);
        O[n2] = __builtin_amdgcn_mfma_f32_16x16x32_bf16(pa[1], v1, O[n2], 0, 0, 0);
      }
      __builtin_amdgcn_s_setprio(0);
    }
    // epilogue: AO[b][s][h*64+d] bf16
    int b = bh >> 4, h = bh & 15;
#pragma unroll
    for (int i = 0; i < 4; ++i) {
      float inv = 1.0f / l_run[i];
      int q = qb + ((lane >> 4) << 2) + i;
#pragma unroll
      for (int n2 = 0; n2 < 4; ++n2) {
        int d = n2 * 16 + (lane & 15);
        AO[((size_t)b * Sn + q) * En + h * 64 + d] = (bf16_t)(O[n2][i] * inv);
      }
    }
  }
}

// ---------------------------------------------------------------- launch
extern "C" void kernel_launch(void* const* d_in, const int* in_sizes, int n_in,
                              void* d_out, int out_size, void* d_ws, size_t ws_size,
                              hipStream_t stream) {
  const float* X     = (const float*)d_in[0];
  // d_in[1] = mask (causal; applied analytically)
  const float* W_qkv = (const float*)d_in[2];
  const float* b_qkv = (const float*)d_in[3];
  const float* W_o   = (const float*)d_in[4];
  const float* b_o   = (const float*)d_in[5];
  float* out = (float*)d_out;

  char* ws = (char*)d_ws;
  bf16_t* Xb  = (bf16_t*)(ws);
  bf16_t* WqT = (bf16_t*)(ws + 8388608);
  bf16_t* WoT = (bf16_t*)(ws + 14680064);
  bf16_t* Qb  = (bf16_t*)(ws + 16777216);
  bf16_t* Kb  = (bf16_t*)(ws + 25165824);
  bf16_t* Vb  = (bf16_t*)(ws + 33554432);
  bf16_t* Vt  = (bf16_t*)(ws + 41943040);
  bf16_t* AO  = (bf16_t*)(ws + 50331648);

  convert_f32_bf16<<<4096, 256, 0, stream>>>(X, Xb, Bn * Sn * En);
  transpose_conv<<<dim3(96, 32), 256, 0, stream>>>(W_qkv, WqT, 1024, 3072);
  transpose_conv<<<dim3(32, 32), 256, 0, stream>>>(W_o, WoT, 1024, 1024);
  gemm_qkv<<<dim3(24, 32), 256, 0, stream>>>(Xb, WqT, b_qkv, Qb, Kb, Vb);
  transpose_v<<<dim3(32, 32), 256, 0, stream>>>(Vb, Vt);
  attn_fwd<<<dim3(16, 32), 256, 0, stream>>>(Qb, Kb, Vt, AO);
  gemm_out<<<dim3(8, 32), 256, 0, stream>>>(AO, WoT, b_o, out);
}

// Round 8
// 229.023 us; speedup vs baseline: 1.1166x; 1.0642x over previous
//
#include <hip/hip_runtime.h>
#include <hip/hip_bf16.h>
#include <cstdint>
#include <cstddef>

typedef __bf16 bf16_t;
typedef __attribute__((ext_vector_type(8))) __bf16 bf16x8;
typedef __attribute__((ext_vector_type(4))) __bf16 bf16x4;
typedef __attribute__((ext_vector_type(4))) float f32x4;

#define AS1 __attribute__((address_space(1)))
#define AS3 __attribute__((address_space(3)))

static constexpr int Bn = 2, Sn = 2048, En = 1024, Hn = 16, Dn = 64;

__device__ __forceinline__ uint32_t cvt_pk_bf16(float lo, float hi) {
  uint32_t r;
  asm("v_cvt_pk_bf16_f32 %0, %1, %2" : "=v"(r) : "v"(lo), "v"(hi));
  return r;
}

// ---------------------------------------------------------------- convert X
__global__ __launch_bounds__(256) void convert_f32_bf16(
    const float* __restrict__ in, bf16_t* __restrict__ out, int n) {
  int i = (blockIdx.x * 256 + threadIdx.x) * 4;
  if (i < n) {
    float4 v = *(const float4*)(in + i);
    bf16x4 o;
    o[0] = (bf16_t)v.x; o[1] = (bf16_t)v.y; o[2] = (bf16_t)v.z; o[3] = (bf16_t)v.w;
    *(bf16x4*)(out + i) = o;
  }
}

// ------------------------------------------- transpose fp32 [R][C] -> bf16 [C][R]
__global__ __launch_bounds__(256) void transpose_conv(
    const float* __restrict__ in, bf16_t* __restrict__ out, int R, int C) {
  __shared__ float tile[32][33];
  int bx = blockIdx.x * 32, by = blockIdx.y * 32;
  int tx = threadIdx.x & 31, ty = threadIdx.x >> 5;  // ty 0..7
#pragma unroll
  for (int i = 0; i < 32; i += 8)
    tile[ty + i][tx] = in[(size_t)(by + ty + i) * C + bx + tx];
  __syncthreads();
#pragma unroll
  for (int i = 0; i < 32; i += 8)
    out[(size_t)(bx + ty + i) * R + by + tx] = (bf16_t)tile[tx][ty + i];
}

// -------------------------------- V [bh][S][64] -> Vt [bh][64][S]  (bf16)
__global__ __launch_bounds__(256) void transpose_v(
    const bf16_t* __restrict__ V, bf16_t* __restrict__ Vt) {
  __shared__ ushort tile[64][65];
  int bh = blockIdx.y, s0 = blockIdx.x * 64;
  int t = threadIdx.x;
  const ushort* src = (const ushort*)(V + ((size_t)bh * Sn + s0) * 64);
#pragma unroll
  for (int p = 0; p < 4; ++p) {
    int s = p * 16 + (t >> 4);
    int c = (t & 15) * 4;
    ushort4 v = *(const ushort4*)(src + (size_t)s * 64 + c);
    tile[s][c] = v.x; tile[s][c + 1] = v.y; tile[s][c + 2] = v.z; tile[s][c + 3] = v.w;
  }
  __syncthreads();
  ushort* dst = (ushort*)(Vt + ((size_t)bh * 64) * Sn + s0);
#pragma unroll
  for (int p = 0; p < 4; ++p) {
    int d = p * 16 + (t >> 4);
    int c = (t & 15) * 4;  // s offset within tile
    ushort4 v;
    v.x = tile[c][d]; v.y = tile[c + 1][d]; v.z = tile[c + 2][d]; v.w = tile[c + 3][d];
    *(ushort4*)(dst + (size_t)d * Sn + c) = v;
  }
}

// ---------------------------------------------------------------- GEMM core
// C = A[M][K] · Bt[N][K]^T. 128x128 tile, BK=32, 256 threads (2x2 waves of
// 64x64). global_load_lds width-16 staging; chunk XOR-swizzle (rule #21).
template <int K_>
__device__ __forceinline__ void gemm_core(
    const bf16_t* __restrict__ A, const bf16_t* __restrict__ Bt,
    f32x4 (&acc)[4][4], int& col0, int& row0) {
  __shared__ bf16_t As[2][128 * 32];
  __shared__ bf16_t Bs[2][128 * 32];
  const int tid = threadIdx.x, lane = tid & 63, wid = tid >> 6;
  const int wm = wid >> 1, wn = wid & 1;
  const int m0 = blockIdx.y * 128, n0 = blockIdx.x * 128;
  const int KT = K_ / 32;

  auto stage = [&](bf16_t* as, bf16_t* bs, int kt) {
    int csw = ((lane & 3) ^ ((lane >> 2) & 3)) * 8;
#pragma unroll
    for (int j = 0; j < 2; ++j) {
      int r0 = wid * 32 + j * 16;
      const bf16_t* ga = A + (size_t)(m0 + r0 + (lane >> 2)) * K_ + kt * 32 + csw;
      __builtin_amdgcn_global_load_lds((const AS1 void*)ga, (AS3 void*)(as + r0 * 32), 16, 0, 0);
      const bf16_t* gb = Bt + (size_t)(n0 + r0 + (lane >> 2)) * K_ + kt * 32 + csw;
      __builtin_amdgcn_global_load_lds((const AS1 void*)gb, (AS3 void*)(bs + r0 * 32), 16, 0, 0);
    }
  };
  auto compute = [&](const bf16_t* as, const bf16_t* bs) {
    bf16x8 af[4], bfr[4];
    uint32_t swz = (uint32_t)(((lane >> 4) ^ (lane & 3)) << 4);
#pragma unroll
    for (int mi = 0; mi < 4; ++mi) {
      uint32_t row = (uint32_t)(wm * 64 + mi * 16 + (lane & 15));
      af[mi] = *(const bf16x8*)((const char*)as + row * 64 + swz);
    }
#pragma unroll
    for (int ni = 0; ni < 4; ++ni) {
      uint32_t row = (uint32_t)(wn * 64 + ni * 16 + (lane & 15));
      bfr[ni] = *(const bf16x8*)((const char*)bs + row * 64 + swz);
    }
#pragma unroll
    for (int mi = 0; mi < 4; ++mi)
#pragma unroll
      for (int ni = 0; ni < 4; ++ni)
        acc[mi][ni] = __builtin_amdgcn_mfma_f32_16x16x32_bf16(af[mi], bfr[ni], acc[mi][ni], 0, 0, 0);
  };

  stage(As[0], Bs[0], 0);
  __syncthreads();
  int cur = 0;
  for (int kt = 0; kt < KT - 1; ++kt) {
    stage(As[cur ^ 1], Bs[cur ^ 1], kt + 1);
    compute(As[cur], Bs[cur]);
    __syncthreads();
    cur ^= 1;
  }
  compute(As[cur], Bs[cur]);
  col0 = n0 + wn * 64 + (lane & 15);
  row0 = m0 + wm * 64 + ((lane >> 4) << 2);
}

__global__ __launch_bounds__(256) void gemm_qkv(
    const bf16_t* __restrict__ A, const bf16_t* __restrict__ Bt,
    const float* __restrict__ bias, bf16_t* __restrict__ Qb,
    bf16_t* __restrict__ Kb, bf16_t* __restrict__ Vb) {
  f32x4 acc[4][4] = {};
  int col0, row0;
  gemm_core<1024>(A, Bt, acc, col0, row0);
#pragma unroll
  for (int ni = 0; ni < 4; ++ni) {
    int n = col0 + ni * 16;
    float bv = bias[n];
    int which = n >> 10, nn = n & 1023;
    int h = nn >> 6, dd = nn & 63;
    bf16_t* dst = which == 0 ? Qb : (which == 1 ? Kb : Vb);
    // Q: fold 1/sqrt(64) AND log2(e) (exp2-softmax) into the stored scale.
    float scl = which == 0 ? 0.125f * 1.44269504f : 1.0f;
#pragma unroll
    for (int mi = 0; mi < 4; ++mi)
#pragma unroll
      for (int i = 0; i < 4; ++i) {
        int m = row0 + mi * 16 + i;
        int b = m >> 11, s = m & 2047;
        float v = (acc[mi][ni][i] + bv) * scl;
        dst[(((size_t)b * Hn + h) * Sn + s) * 64 + dd] = (bf16_t)v;
      }
  }
}

__global__ __launch_bounds__(256) void gemm_out(
    const bf16_t* __restrict__ A, const bf16_t* __restrict__ Bt,
    const float* __restrict__ bias, float* __restrict__ out) {
  f32x4 acc[4][4] = {};
  int col0, row0;
  gemm_core<1024>(A, Bt, acc, col0, row0);
#pragma unroll
  for (int ni = 0; ni < 4; ++ni) {
    int n = col0 + ni * 16;
    float bv = bias[n];
#pragma unroll
    for (int mi = 0; mi < 4; ++mi)
#pragma unroll
      for (int i = 0; i < 4; ++i) {
        int m = row0 + mi * 16 + i;
        out[(size_t)m * En + n] = acc[mi][ni][i] + bv;
      }
  }
}

// -------------------------------------------------------- flash attention fwd
// grid (16, B*H), 256 threads. R5 skeleton (causal pairing {pr, 31-pr}, K/V
// 2-buffer via global_load_lds w16, pre-swizzled source, vmcnt(0)+barrier).
// NEW: swapped-QK in-register softmax (T12 idea):
//   S^T = mfma(K_frag, Q_frag)  -> lane holds 16 kv values for q = lane&15
//   row max/sum: in-lane + shfl_xor(16,32)  (2 shuffles, was 16)
//   m, l scalars per lane; P -> bf16 via v_cvt_pk_bf16_f32; PV B-fragment
//   built with 16 ds_bpermute + cndmask (no P LDS round-trip, no lgkm drain)
//   O^T = mfma(Vt_frag, P_frag); epilogue transposes O via per-wave LDS once
//   per segment. exp2-softmax (log2e in Q), defer-max thr 11.5, setprio (T5).
__global__ __launch_bounds__(256) void attn_fwd(
    const bf16_t* __restrict__ Qb, const bf16_t* __restrict__ Kb,
    const bf16_t* __restrict__ Vt, bf16_t* __restrict__ AO) {
  __shared__ bf16_t Ks[2][64 * 64];
  __shared__ bf16_t Vs[2][64 * 64];
  __shared__ bf16_t Ps[4][16 * 64];   // epilogue transpose only
  const int tid = threadIdx.x, lane = tid & 63, wid = tid >> 6;
  const int bh = blockIdx.y;
  const int pr = blockIdx.x;  // pair index 0..15

  const int rl = lane >> 3;   // row within 8-row group
  const int cp = lane & 7;    // physical 16B chunk
  auto issueKV = [&](int buf, int t) {
#pragma unroll
    for (int j = 0; j < 2; ++j) {
      int r = wid * 16 + j * 8 + rl;
      int sc = cp ^ rl;       // source logical chunk (pre-swizzle, r&7==rl)
      const bf16_t* gk = Kb + (((size_t)bh * Sn + t * 64 + r) << 6) + (sc << 3);
      __builtin_amdgcn_global_load_lds((const AS1 void*)gk,
          (AS3 void*)(&Ks[buf][wid * 1024 + j * 512]), 16, 0, 0);
      const bf16_t* gv = Vt + ((size_t)bh * 64 + r) * Sn + t * 64 + (sc << 3);
      __builtin_amdgcn_global_load_lds((const AS1 void*)gv,
          (AS3 void*)(&Vs[buf][wid * 1024 + j * 512]), 16, 0, 0);
    }
  };

  // bpermute source indices for the P-fragment build (byte = lane*4):
  // srcA pulls from lane 32*(g&1) + q; srcB = srcA + 16 lanes.
  const int srcA = (((lane & 15) + ((lane & 16) << 1)) << 2);
  const int srcB = srcA + 64;
  const bool hi = lane >= 32;

  int buf = 0;
  issueKV(0, 0);

  for (int seg = 0; seg < 2; ++seg) {
    const int q_tile = seg ? 31 - pr : pr;
    const int ntseg = q_tile + 1;
    const int qb = q_tile * 64 + wid * 16;
    const int qmy = qb + (lane & 15);

    bf16x8 aq[2];
    {
      const bf16_t* qp = Qb + ((size_t)bh * Sn + qb + (lane & 15)) * 64 + ((lane >> 4) << 3);
      aq[0] = *(const bf16x8*)qp;
      aq[1] = *(const bf16x8*)(qp + 32);
    }
    f32x4 O[4] = {};
    float m_run = -1e30f, l_run = 0.f;

    for (int t = 0; t < ntseg; ++t) {
      asm volatile("s_waitcnt vmcnt(0)" ::: "memory");
      __syncthreads();
      if (t + 1 < ntseg) issueKV(buf ^ 1, t + 1);
      else if (seg == 0) issueKV(buf ^ 1, 0);  // prefetch segment 1, tile 0
      const char* ksb = (const char*)Ks[buf];
      const char* vsb = (const char*)Vs[buf];
      // S^T = K · Q^T : lane holds S[kv = ni*16 + 4*(lane>>4)+i][q = lane&15]
      f32x4 sc[4];
      __builtin_amdgcn_s_setprio(1);
#pragma unroll
      for (int ni = 0; ni < 4; ++ni) {
        int kvr = ni * 16 + (lane & 15);
        uint32_t o0 = (uint32_t)(kvr * 128 + ((lane >> 4) << 4)) ^ (uint32_t)((kvr & 7) << 4);
        uint32_t o1 = (uint32_t)(kvr * 128 + 64 + ((lane >> 4) << 4)) ^ (uint32_t)((kvr & 7) << 4);
        bf16x8 b0 = *(const bf16x8*)(ksb + o0);
        bf16x8 b1 = *(const bf16x8*)(ksb + o1);
        f32x4 z = {};
        z = __builtin_amdgcn_mfma_f32_16x16x32_bf16(b0, aq[0], z, 0, 0, 0);
        sc[ni] = __builtin_amdgcn_mfma_f32_16x16x32_bf16(b1, aq[1], z, 0, 0, 0);
      }
      __builtin_amdgcn_s_setprio(0);
      if (t == ntseg - 1) {  // diagonal tile: causal mask (kv > q -> -inf)
#pragma unroll
        for (int ni = 0; ni < 4; ++ni) {
          int kvbase = t * 64 + ni * 16 + ((lane >> 4) << 2);
#pragma unroll
          for (int i = 0; i < 4; ++i)
            if (kvbase + i > qmy) sc[ni][i] = -1e30f;
        }
      }
      // tile max for q = lane&15: in-lane over 16, then across the 4 groups
      float mt = sc[0][0];
#pragma unroll
      for (int ni = 0; ni < 4; ++ni)
#pragma unroll
        for (int i = 0; i < 4; ++i) mt = fmaxf(mt, sc[ni][i]);
      mt = fmaxf(mt, __shfl_xor(mt, 16));
      mt = fmaxf(mt, __shfl_xor(mt, 32));
      // defer-max: rescale only when max grew by > 11.5 (log2 units)
      if (!__all(mt <= m_run + 11.5f)) {
        float mn = fmaxf(m_run, mt);
        float s = __builtin_exp2f(m_run - mn);
        m_run = mn;
        l_run *= s;
#pragma unroll
        for (int n2 = 0; n2 < 4; ++n2)
#pragma unroll
          for (int i = 0; i < 4; ++i) O[n2][i] *= s;
      }
      // P = exp2(S - m); pack to bf16 pairs
      float rs = 0.f;
      uint32_t pk[4][2];
#pragma unroll
      for (int ni = 0; ni < 4; ++ni) {
        float p0 = __builtin_exp2f(sc[ni][0] - m_run);
        float p1 = __builtin_exp2f(sc[ni][1] - m_run);
        float p2 = __builtin_exp2f(sc[ni][2] - m_run);
        float p3 = __builtin_exp2f(sc[ni][3] - m_run);
        rs += (p0 + p1) + (p2 + p3);
        pk[ni][0] = cvt_pk_bf16(p0, p1);
        pk[ni][1] = cvt_pk_bf16(p2, p3);
      }
      rs += __shfl_xor(rs, 16);
      rs += __shfl_xor(rs, 32);
      l_run += rs;
      // build PV B-fragment: W[t][w] = pk[2t+(g>>1)][w&1] from lane
      // 32*(g&1) + 16*(w>>1) + q   (verified mapping)
      union U8 { uint32_t u[4]; bf16x8 v; } pw0, pw1;
#pragma unroll
      for (int w = 0; w < 4; ++w) {
        int srci = (w < 2) ? srcA : srcB;
        uint32_t x0 = (uint32_t)__builtin_amdgcn_ds_bpermute(srci, (int)pk[0][w & 1]);
        uint32_t y0 = (uint32_t)__builtin_amdgcn_ds_bpermute(srci, (int)pk[1][w & 1]);
        pw0.u[w] = hi ? y0 : x0;
        uint32_t x1 = (uint32_t)__builtin_amdgcn_ds_bpermute(srci, (int)pk[2][w & 1]);
        uint32_t y1 = (uint32_t)__builtin_amdgcn_ds_bpermute(srci, (int)pk[3][w & 1]);
        pw1.u[w] = hi ? y1 : x1;
      }
      // O^T += V^T · P^T : lane holds O[q = lane&15][d = n2*16 + 4*(lane>>4)+i]
      __builtin_amdgcn_s_setprio(1);
#pragma unroll
      for (int n2 = 0; n2 < 4; ++n2) {
        int dr = n2 * 16 + (lane & 15);
        uint32_t o0 = (uint32_t)(dr * 128 + ((lane >> 4) << 4)) ^ (uint32_t)((dr & 7) << 4);
        uint32_t o1 = (uint32_t)(dr * 128 + 64 + ((lane >> 4) << 4)) ^ (uint32_t)((dr & 7) << 4);
        bf16x8 v0 = *(const bf16x8*)(vsb + o0);
        bf16x8 v1 = *(const bf16x8*)(vsb + o1);
        O[n2] = __builtin_amdgcn_mfma_f32_16x16x32_bf16(v0, pw0.v, O[n2], 0, 0, 0);
        O[n2] = __builtin_amdgcn_mfma_f32_16x16x32_bf16(v1, pw1.v, O[n2], 0, 0, 0);
      }
      __builtin_amdgcn_s_setprio(0);
      buf ^= 1;
    }
    // epilogue: O^T -> row-major via per-wave LDS (XOR-swizzled), then store
    char* pw = (char*)Ps[wid];
    const float inv = 1.0f / l_run;
    const int ql = lane & 15, g = lane >> 4;
#pragma unroll
    for (int n2 = 0; n2 < 4; ++n2)
#pragma unroll
      for (int p2 = 0; p2 < 2; ++p2) {
        uint32_t w = cvt_pk_bf16(O[n2][2 * p2] * inv, O[n2][2 * p2 + 1] * inv);
        uint32_t byte = (uint32_t)(ql * 128 + n2 * 32 + g * 8 + p2 * 4) ^ (uint32_t)((ql & 7) << 4);
        *(uint32_t*)(pw + byte) = w;
      }
    asm volatile("s_waitcnt lgkmcnt(0)" ::: "memory");
    __builtin_amdgcn_sched_barrier(0);
    int b = bh >> 4, h = bh & 15;
#pragma unroll
    for (int i = 0; i < 4; ++i) {
      int ql2 = (g << 2) + i;
      int qrow = qb + ql2;
#pragma unroll
      for (int n2 = 0; n2 < 4; ++n2) {
        int d = n2 * 16 + ql;
        uint32_t byte = (uint32_t)(ql2 * 128 + d * 2) ^ (uint32_t)((ql2 & 7) << 4);
        AO[((size_t)b * Sn + qrow) * En + h * 64 + d] = *(bf16_t*)(pw + byte);
      }
    }
  }
}

// ---------------------------------------------------------------- launch
extern "C" void kernel_launch(void* const* d_in, const int* in_sizes, int n_in,
                              void* d_out, int out_size, void* d_ws, size_t ws_size,
                              hipStream_t stream) {
  const float* X     = (const float*)d_in[0];
  // d_in[1] = mask (causal; applied analytically)
  const float* W_qkv = (const float*)d_in[2];
  const float* b_qkv = (const float*)d_in[3];
  const float* W_o   = (const float*)d_in[4];
  const float* b_o   = (const float*)d_in[5];
  float* out = (float*)d_out;

  char* ws = (char*)d_ws;
  bf16_t* Xb  = (bf16_t*)(ws);
  bf16_t* WqT = (bf16_t*)(ws + 8388608);
  bf16_t* WoT = (bf16_t*)(ws + 14680064);
  bf16_t* Qb  = (bf16_t*)(ws + 16777216);
  bf16_t* Kb  = (bf16_t*)(ws + 25165824);
  bf16_t* Vb  = (bf16_t*)(ws + 33554432);
  bf16_t* Vt  = (bf16_t*)(ws + 41943040);
  bf16_t* AO  = (bf16_t*)(ws + 50331648);

  convert_f32_bf16<<<4096, 256, 0, stream>>>(X, Xb, Bn * Sn * En);
  transpose_conv<<<dim3(96, 32), 256, 0, stream>>>(W_qkv, WqT, 1024, 3072);
  transpose_conv<<<dim3(32, 32), 256, 0, stream>>>(W_o, WoT, 1024, 1024);
  gemm_qkv<<<dim3(24, 32), 256, 0, stream>>>(Xb, WqT, b_qkv, Qb, Kb, Vb);
  transpose_v<<<dim3(32, 32), 256, 0, stream>>>(Vb, Vt);
  attn_fwd<<<dim3(16, 32), 256, 0, stream>>>(Qb, Kb, Vt, AO);
  gemm_out<<<dim3(8, 32), 256, 0, stream>>>(AO, WoT, b_o, out);
}

// Round 10
// 224.425 us; speedup vs baseline: 1.1395x; 1.0205x over previous
//
#include <hip/hip_runtime.h>
#include <hip/hip_bf16.h>
#include <cstdint>
#include <cstddef>

typedef __bf16 bf16_t;
typedef __attribute__((ext_vector_type(8))) __bf16 bf16x8;
typedef __attribute__((ext_vector_type(4))) __bf16 bf16x4;
typedef __attribute__((ext_vector_type(4))) float f32x4;

#define AS1 __attribute__((address_space(1)))
#define AS3 __attribute__((address_space(3)))

static constexpr int Bn = 2, Sn = 2048, En = 1024, Hn = 16, Dn = 64;

__device__ __forceinline__ uint32_t cvt_pk_bf16(float lo, float hi) {
  uint32_t r;
  asm("v_cvt_pk_bf16_f32 %0, %1, %2" : "=v"(r) : "v"(lo), "v"(hi));
  return r;
}

// ---------------------------------------------------------------- convert X
__global__ __launch_bounds__(256) void convert_f32_bf16(
    const float* __restrict__ in, bf16_t* __restrict__ out, int n) {
  int i = (blockIdx.x * 256 + threadIdx.x) * 4;
  if (i < n) {
    float4 v = *(const float4*)(in + i);
    bf16x4 o;
    o[0] = (bf16_t)v.x; o[1] = (bf16_t)v.y; o[2] = (bf16_t)v.z; o[3] = (bf16_t)v.w;
    *(bf16x4*)(out + i) = o;
  }
}

// ------------------------------------------- transpose fp32 [R][C] -> bf16 [C][R]
__global__ __launch_bounds__(256) void transpose_conv(
    const float* __restrict__ in, bf16_t* __restrict__ out, int R, int C) {
  __shared__ float tile[32][33];
  int bx = blockIdx.x * 32, by = blockIdx.y * 32;
  int tx = threadIdx.x & 31, ty = threadIdx.x >> 5;  // ty 0..7
#pragma unroll
  for (int i = 0; i < 32; i += 8)
    tile[ty + i][tx] = in[(size_t)(by + ty + i) * C + bx + tx];
  __syncthreads();
#pragma unroll
  for (int i = 0; i < 32; i += 8)
    out[(size_t)(bx + ty + i) * R + by + tx] = (bf16_t)tile[tx][ty + i];
}

// -------------------------------- V [bh][S][64] -> Vt [bh][64][S]  (bf16)
__global__ __launch_bounds__(256) void transpose_v(
    const bf16_t* __restrict__ V, bf16_t* __restrict__ Vt) {
  __shared__ ushort tile[64][65];
  int bh = blockIdx.y, s0 = blockIdx.x * 64;
  int t = threadIdx.x;
  const ushort* src = (const ushort*)(V + ((size_t)bh * Sn + s0) * 64);
#pragma unroll
  for (int p = 0; p < 4; ++p) {
    int s = p * 16 + (t >> 4);
    int c = (t & 15) * 4;
    ushort4 v = *(const ushort4*)(src + (size_t)s * 64 + c);
    tile[s][c] = v.x; tile[s][c + 1] = v.y; tile[s][c + 2] = v.z; tile[s][c + 3] = v.w;
  }
  __syncthreads();
  ushort* dst = (ushort*)(Vt + ((size_t)bh * 64) * Sn + s0);
#pragma unroll
  for (int p = 0; p < 4; ++p) {
    int d = p * 16 + (t >> 4);
    int c = (t & 15) * 4;  // s offset within tile
    ushort4 v;
    v.x = tile[c][d]; v.y = tile[c + 1][d]; v.z = tile[c + 2][d]; v.w = tile[c + 3][d];
    *(ushort4*)(dst + (size_t)d * Sn + c) = v;
  }
}

// ---------------------------------------------------------------- GEMM core
// C = A[M][K] · Bt[N][K]^T. 128x128 tile, BK=32, 256 threads (2x2 waves of
// 64x64). global_load_lds width-16 staging; chunk XOR-swizzle (rule #21).
template <int K_>
__device__ __forceinline__ void gemm_core(
    const bf16_t* __restrict__ A, const bf16_t* __restrict__ Bt,
    f32x4 (&acc)[4][4], int& col0, int& row0) {
  __shared__ bf16_t As[2][128 * 32];
  __shared__ bf16_t Bs[2][128 * 32];
  const int tid = threadIdx.x, lane = tid & 63, wid = tid >> 6;
  const int wm = wid >> 1, wn = wid & 1;
  const int m0 = blockIdx.y * 128, n0 = blockIdx.x * 128;
  const int KT = K_ / 32;

  auto stage = [&](bf16_t* as, bf16_t* bs, int kt) {
    int csw = ((lane & 3) ^ ((lane >> 2) & 3)) * 8;
#pragma unroll
    for (int j = 0; j < 2; ++j) {
      int r0 = wid * 32 + j * 16;
      const bf16_t* ga = A + (size_t)(m0 + r0 + (lane >> 2)) * K_ + kt * 32 + csw;
      __builtin_amdgcn_global_load_lds((const AS1 void*)ga, (AS3 void*)(as + r0 * 32), 16, 0, 0);
      const bf16_t* gb = Bt + (size_t)(n0 + r0 + (lane >> 2)) * K_ + kt * 32 + csw;
      __builtin_amdgcn_global_load_lds((const AS1 void*)gb, (AS3 void*)(bs + r0 * 32), 16, 0, 0);
    }
  };
  auto compute = [&](const bf16_t* as, const bf16_t* bs) {
    bf16x8 af[4], bfr[4];
    uint32_t swz = (uint32_t)(((lane >> 4) ^ (lane & 3)) << 4);
#pragma unroll
    for (int mi = 0; mi < 4; ++mi) {
      uint32_t row = (uint32_t)(wm * 64 + mi * 16 + (lane & 15));
      af[mi] = *(const bf16x8*)((const char*)as + row * 64 + swz);
    }
#pragma unroll
    for (int ni = 0; ni < 4; ++ni) {
      uint32_t row = (uint32_t)(wn * 64 + ni * 16 + (lane & 15));
      bfr[ni] = *(const bf16x8*)((const char*)bs + row * 64 + swz);
    }
#pragma unroll
    for (int mi = 0; mi < 4; ++mi)
#pragma unroll
      for (int ni = 0; ni < 4; ++ni)
        acc[mi][ni] = __builtin_amdgcn_mfma_f32_16x16x32_bf16(af[mi], bfr[ni], acc[mi][ni], 0, 0, 0);
  };

  stage(As[0], Bs[0], 0);
  __syncthreads();
  int cur = 0;
  for (int kt = 0; kt < KT - 1; ++kt) {
    stage(As[cur ^ 1], Bs[cur ^ 1], kt + 1);
    compute(As[cur], Bs[cur]);
    __syncthreads();
    cur ^= 1;
  }
  compute(As[cur], Bs[cur]);
  col0 = n0 + wn * 64 + (lane & 15);
  row0 = m0 + wm * 64 + ((lane >> 4) << 2);
}

__global__ __launch_bounds__(256) void gemm_qkv(
    const bf16_t* __restrict__ A, const bf16_t* __restrict__ Bt,
    const float* __restrict__ bias, bf16_t* __restrict__ Qb,
    bf16_t* __restrict__ Kb, bf16_t* __restrict__ Vb) {
  f32x4 acc[4][4] = {};
  int col0, row0;
  gemm_core<1024>(A, Bt, acc, col0, row0);
#pragma unroll
  for (int ni = 0; ni < 4; ++ni) {
    int n = col0 + ni * 16;
    float bv = bias[n];
    int which = n >> 10, nn = n & 1023;
    int h = nn >> 6, dd = nn & 63;
    bf16_t* dst = which == 0 ? Qb : (which == 1 ? Kb : Vb);
    // Q: fold 1/sqrt(64) AND log2(e) (exp2-softmax) into the stored scale.
    float scl = which == 0 ? 0.125f * 1.44269504f : 1.0f;
#pragma unroll
    for (int mi = 0; mi < 4; ++mi)
#pragma unroll
      for (int i = 0; i < 4; ++i) {
        int m = row0 + mi * 16 + i;
        int b = m >> 11, s = m & 2047;
        float v = (acc[mi][ni][i] + bv) * scl;
        dst[(((size_t)b * Hn + h) * Sn + s) * 64 + dd] = (bf16_t)v;
      }
  }
}

__global__ __launch_bounds__(256) void gemm_out(
    const bf16_t* __restrict__ A, const bf16_t* __restrict__ Bt,
    const float* __restrict__ bias, float* __restrict__ out) {
  f32x4 acc[4][4] = {};
  int col0, row0;
  gemm_core<1024>(A, Bt, acc, col0, row0);
#pragma unroll
  for (int ni = 0; ni < 4; ++ni) {
    int n = col0 + ni * 16;
    float bv = bias[n];
#pragma unroll
    for (int mi = 0; mi < 4; ++mi)
#pragma unroll
      for (int i = 0; i < 4; ++i) {
        int m = row0 + mi * 16 + i;
        out[(size_t)m * En + n] = acc[mi][ni][i] + bv;
      }
  }
}

// -------------------------------------------------------- flash attention fwd
// grid (32=bh, 16=pr), 256 threads. XCD-locality (T1): linear block id =
// bh + 32*pr => id%8 = bh%8, so each XCD serves only 4 bh => K/V working set
// 2 MB < 4 MB per-XCD L2; K/V re-reads become L2 hits.
// R5 skeleton (causal pairing {pr, 31-pr}, K/V 2-buffer via global_load_lds
// w16, pre-swizzled source, vmcnt(0)+barrier) + swapped-QK in-register
// softmax: S^T = mfma(K,Q), lane owns q=lane&15; P->bf16 via cvt_pk;
// PV B-frag built with ds_bpermute; O^T = mfma(Vt,P); epilogue transposes
// via LDS. exp2-softmax, defer-max thr 11.5, setprio (T5).
__global__ __launch_bounds__(256) void attn_fwd(
    const bf16_t* __restrict__ Qb, const bf16_t* __restrict__ Kb,
    const bf16_t* __restrict__ Vt, bf16_t* __restrict__ AO) {
  __shared__ bf16_t Ks[2][64 * 64];
  __shared__ bf16_t Vs[2][64 * 64];
  __shared__ bf16_t Ps[4][16 * 64];   // epilogue transpose only
  const int tid = threadIdx.x, lane = tid & 63, wid = tid >> 6;
  const int bh = blockIdx.x;  // SWAPPED: bh on x for XCD locality
  const int pr = blockIdx.y;  // pair index 0..15

  const int rl = lane >> 3;   // row within 8-row group
  const int cp = lane & 7;    // physical 16B chunk
  auto issueKV = [&](int buf, int t) {
#pragma unroll
    for (int j = 0; j < 2; ++j) {
      int r = wid * 16 + j * 8 + rl;
      int sc = cp ^ rl;       // source logical chunk (pre-swizzle, r&7==rl)
      const bf16_t* gk = Kb + (((size_t)bh * Sn + t * 64 + r) << 6) + (sc << 3);
      __builtin_amdgcn_global_load_lds((const AS1 void*)gk,
          (AS3 void*)(&Ks[buf][wid * 1024 + j * 512]), 16, 0, 0);
      const bf16_t* gv = Vt + ((size_t)bh * 64 + r) * Sn + t * 64 + (sc << 3);
      __builtin_amdgcn_global_load_lds((const AS1 void*)gv,
          (AS3 void*)(&Vs[buf][wid * 1024 + j * 512]), 16, 0, 0);
    }
  };

  // bpermute source indices for the P-fragment build (byte = lane*4):
  // srcA pulls from lane 32*(g&1) + q; srcB = srcA + 16 lanes.
  const int srcA = (((lane & 15) + ((lane & 16) << 1)) << 2);
  const int srcB = srcA + 64;
  const bool hi = lane >= 32;

  int buf = 0;
  issueKV(0, 0);

  for (int seg = 0; seg < 2; ++seg) {
    const int q_tile = seg ? 31 - pr : pr;
    const int ntseg = q_tile + 1;
    const int qb = q_tile * 64 + wid * 16;
    const int qmy = qb + (lane & 15);

    bf16x8 aq[2];
    {
      const bf16_t* qp = Qb + ((size_t)bh * Sn + qb + (lane & 15)) * 64 + ((lane >> 4) << 3);
      aq[0] = *(const bf16x8*)qp;
      aq[1] = *(const bf16x8*)(qp + 32);
    }
    f32x4 O[4] = {};
    float m_run = -1e30f, l_run = 0.f;

    for (int t = 0; t < ntseg; ++t) {
      asm volatile("s_waitcnt vmcnt(0)" ::: "memory");
      __syncthreads();
      if (t + 1 < ntseg) issueKV(buf ^ 1, t + 1);
      else if (seg == 0) issueKV(buf ^ 1, 0);  // prefetch segment 1, tile 0
      const char* ksb = (const char*)Ks[buf];
      const char* vsb = (const char*)Vs[buf];
      // S^T = K · Q^T : lane holds S[kv = ni*16 + 4*(lane>>4)+i][q = lane&15]
      f32x4 sc[4];
      __builtin_amdgcn_s_setprio(1);
#pragma unroll
      for (int ni = 0; ni < 4; ++ni) {
        int kvr = ni * 16 + (lane & 15);
        uint32_t o0 = (uint32_t)(kvr * 128 + ((lane >> 4) << 4)) ^ (uint32_t)((kvr & 7) << 4);
        uint32_t o1 = (uint32_t)(kvr * 128 + 64 + ((lane >> 4) << 4)) ^ (uint32_t)((kvr & 7) << 4);
        bf16x8 b0 = *(const bf16x8*)(ksb + o0);
        bf16x8 b1 = *(const bf16x8*)(ksb + o1);
        f32x4 z = {};
        z = __builtin_amdgcn_mfma_f32_16x16x32_bf16(b0, aq[0], z, 0, 0, 0);
        sc[ni] = __builtin_amdgcn_mfma_f32_16x16x32_bf16(b1, aq[1], z, 0, 0, 0);
      }
      __builtin_amdgcn_s_setprio(0);
      if (t == ntseg - 1) {  // diagonal tile: causal mask (kv > q -> -inf)
#pragma unroll
        for (int ni = 0; ni < 4; ++ni) {
          int kvbase = t * 64 + ni * 16 + ((lane >> 4) << 2);
#pragma unroll
          for (int i = 0; i < 4; ++i)
            if (kvbase + i > qmy) sc[ni][i] = -1e30f;
        }
      }
      // tile max for q = lane&15: in-lane over 16, then across the 4 groups
      float mt = sc[0][0];
#pragma unroll
      for (int ni = 0; ni < 4; ++ni)
#pragma unroll
        for (int i = 0; i < 4; ++i) mt = fmaxf(mt, sc[ni][i]);
      mt = fmaxf(mt, __shfl_xor(mt, 16));
      mt = fmaxf(mt, __shfl_xor(mt, 32));
      // defer-max: rescale only when max grew by > 11.5 (log2 units)
      if (!__all(mt <= m_run + 11.5f)) {
        float mn = fmaxf(m_run, mt);
        float s = __builtin_exp2f(m_run - mn);
        m_run = mn;
        l_run *= s;
#pragma unroll
        for (int n2 = 0; n2 < 4; ++n2)
#pragma unroll
          for (int i = 0; i < 4; ++i) O[n2][i] *= s;
      }
      // P = exp2(S - m); pack to bf16 pairs
      float rs = 0.f;
      uint32_t pk[4][2];
#pragma unroll
      for (int ni = 0; ni < 4; ++ni) {
        float p0 = __builtin_exp2f(sc[ni][0] - m_run);
        float p1 = __builtin_exp2f(sc[ni][1] - m_run);
        float p2 = __builtin_exp2f(sc[ni][2] - m_run);
        float p3 = __builtin_exp2f(sc[ni][3] - m_run);
        rs += (p0 + p1) + (p2 + p3);
        pk[ni][0] = cvt_pk_bf16(p0, p1);
        pk[ni][1] = cvt_pk_bf16(p2, p3);
      }
      rs += __shfl_xor(rs, 16);
      rs += __shfl_xor(rs, 32);
      l_run += rs;
      // build PV B-fragment: W[t][w] = pk[2t+(g>>1)][w&1] from lane
      // 32*(g&1) + 16*(w>>1) + q   (verified mapping)
      union U8 { uint32_t u[4]; bf16x8 v; } pw0, pw1;
#pragma unroll
      for (int w = 0; w < 4; ++w) {
        int srci = (w < 2) ? srcA : srcB;
        uint32_t x0 = (uint32_t)__builtin_amdgcn_ds_bpermute(srci, (int)pk[0][w & 1]);
        uint32_t y0 = (uint32_t)__builtin_amdgcn_ds_bpermute(srci, (int)pk[1][w & 1]);
        pw0.u[w] = hi ? y0 : x0;
        uint32_t x1 = (uint32_t)__builtin_amdgcn_ds_bpermute(srci, (int)pk[2][w & 1]);
        uint32_t y1 = (uint32_t)__builtin_amdgcn_ds_bpermute(srci, (int)pk[3][w & 1]);
        pw1.u[w] = hi ? y1 : x1;
      }
      // O^T += V^T · P^T : lane holds O[q = lane&15][d = n2*16 + 4*(lane>>4)+i]
      __builtin_amdgcn_s_setprio(1);
#pragma unroll
      for (int n2 = 0; n2 < 4; ++n2) {
        int dr = n2 * 16 + (lane & 15);
        uint32_t o0 = (uint32_t)(dr * 128 + ((lane >> 4) << 4)) ^ (uint32_t)((dr & 7) << 4);
        uint32_t o1 = (uint32_t)(dr * 128 + 64 + ((lane >> 4) << 4)) ^ (uint32_t)((dr & 7) << 4);
        bf16x8 v0 = *(const bf16x8*)(vsb + o0);
        bf16x8 v1 = *(const bf16x8*)(vsb + o1);
        O[n2] = __builtin_amdgcn_mfma_f32_16x16x32_bf16(v0, pw0.v, O[n2], 0, 0, 0);
        O[n2] = __builtin_amdgcn_mfma_f32_16x16x32_bf16(v1, pw1.v, O[n2], 0, 0, 0);
      }
      __builtin_amdgcn_s_setprio(0);
      buf ^= 1;
    }
    // epilogue: O^T -> row-major via per-wave LDS (XOR-swizzled), then store
    char* pw = (char*)Ps[wid];
    const float inv = 1.0f / l_run;
    const int ql = lane & 15, g = lane >> 4;
#pragma unroll
    for (int n2 = 0; n2 < 4; ++n2)
#pragma unroll
      for (int p2 = 0; p2 < 2; ++p2) {
        uint32_t w = cvt_pk_bf16(O[n2][2 * p2] * inv, O[n2][2 * p2 + 1] * inv);
        uint32_t byte = (uint32_t)(ql * 128 + n2 * 32 + g * 8 + p2 * 4) ^ (uint32_t)((ql & 7) << 4);
        *(uint32_t*)(pw + byte) = w;
      }
    asm volatile("s_waitcnt lgkmcnt(0)" ::: "memory");
    __builtin_amdgcn_sched_barrier(0);
    int b = bh >> 4, h = bh & 15;
#pragma unroll
    for (int i = 0; i < 4; ++i) {
      int ql2 = (g << 2) + i;
      int qrow = qb + ql2;
#pragma unroll
      for (int n2 = 0; n2 < 4; ++n2) {
        int d = n2 * 16 + ql;
        uint32_t byte = (uint32_t)(ql2 * 128 + d * 2) ^ (uint32_t)((ql2 & 7) << 4);
        AO[((size_t)b * Sn + qrow) * En + h * 64 + d] = *(bf16_t*)(pw + byte);
      }
    }
  }
}

// ---------------------------------------------------------------- launch
extern "C" void kernel_launch(void* const* d_in, const int* in_sizes, int n_in,
                              void* d_out, int out_size, void* d_ws, size_t ws_size,
                              hipStream_t stream) {
  const float* X     = (const float*)d_in[0];
  // d_in[1] = mask (causal; applied analytically)
  const float* W_qkv = (const float*)d_in[2];
  const float* b_qkv = (const float*)d_in[3];
  const float* W_o   = (const float*)d_in[4];
  const float* b_o   = (const float*)d_in[5];
  float* out = (float*)d_out;

  char* ws = (char*)d_ws;
  bf16_t* Xb  = (bf16_t*)(ws);
  bf16_t* WqT = (bf16_t*)(ws + 8388608);
  bf16_t* WoT = (bf16_t*)(ws + 14680064);
  bf16_t* Qb  = (bf16_t*)(ws + 16777216);
  bf16_t* Kb  = (bf16_t*)(ws + 25165824);
  bf16_t* Vb  = (bf16_t*)(ws + 33554432);
  bf16_t* Vt  = (bf16_t*)(ws + 41943040);
  bf16_t* AO  = (bf16_t*)(ws + 50331648);

  convert_f32_bf16<<<4096, 256, 0, stream>>>(X, Xb, Bn * Sn * En);
  transpose_conv<<<dim3(96, 32), 256, 0, stream>>>(W_qkv, WqT, 1024, 3072);
  transpose_conv<<<dim3(32, 32), 256, 0, stream>>>(W_o, WoT, 1024, 1024);
  gemm_qkv<<<dim3(24, 32), 256, 0, stream>>>(Xb, WqT, b_qkv, Qb, Kb, Vb);
  transpose_v<<<dim3(32, 32), 256, 0, stream>>>(Vb, Vt);
  attn_fwd<<<dim3(32, 16), 256, 0, stream>>>(Qb, Kb, Vt, AO);
  gemm_out<<<dim3(8, 32), 256, 0, stream>>>(AO, WoT, b_o, out);
}

// Round 11
// 216.627 us; speedup vs baseline: 1.1805x; 1.0360x over previous
//
#include <hip/hip_runtime.h>
#include <hip/hip_bf16.h>
#include <cstdint>
#include <cstddef>

typedef __bf16 bf16_t;
typedef __attribute__((ext_vector_type(8))) __bf16 bf16x8;
typedef __attribute__((ext_vector_type(4))) __bf16 bf16x4;
typedef __attribute__((ext_vector_type(4))) float f32x4;

#define AS1 __attribute__((address_space(1)))
#define AS3 __attribute__((address_space(3)))

static constexpr int Bn = 2, Sn = 2048, En = 1024, Hn = 16, Dn = 64;

__device__ __forceinline__ uint32_t cvt_pk_bf16(float lo, float hi) {
  uint32_t r;
  asm("v_cvt_pk_bf16_f32 %0, %1, %2" : "=v"(r) : "v"(lo), "v"(hi));
  return r;
}

// ---------------------------------------------------------------- convert X
__global__ __launch_bounds__(256) void convert_f32_bf16(
    const float* __restrict__ in, bf16_t* __restrict__ out, int n) {
  int i = (blockIdx.x * 256 + threadIdx.x) * 4;
  if (i < n) {
    float4 v = *(const float4*)(in + i);
    bf16x4 o;
    o[0] = (bf16_t)v.x; o[1] = (bf16_t)v.y; o[2] = (bf16_t)v.z; o[3] = (bf16_t)v.w;
    *(bf16x4*)(out + i) = o;
  }
}

// ------------------------------------------- transpose fp32 [R][C] -> bf16 [C][R]
__global__ __launch_bounds__(256) void transpose_conv(
    const float* __restrict__ in, bf16_t* __restrict__ out, int R, int C) {
  __shared__ float tile[32][33];
  int bx = blockIdx.x * 32, by = blockIdx.y * 32;
  int tx = threadIdx.x & 31, ty = threadIdx.x >> 5;  // ty 0..7
#pragma unroll
  for (int i = 0; i < 32; i += 8)
    tile[ty + i][tx] = in[(size_t)(by + ty + i) * C + bx + tx];
  __syncthreads();
#pragma unroll
  for (int i = 0; i < 32; i += 8)
    out[(size_t)(bx + ty + i) * R + by + tx] = (bf16_t)tile[tx][ty + i];
}

// -------------------------------- V [bh][S][64] -> Vt [bh][64][S]  (bf16)
__global__ __launch_bounds__(256) void transpose_v(
    const bf16_t* __restrict__ V, bf16_t* __restrict__ Vt) {
  __shared__ ushort tile[64][65];
  int bh = blockIdx.y, s0 = blockIdx.x * 64;
  int t = threadIdx.x;
  const ushort* src = (const ushort*)(V + ((size_t)bh * Sn + s0) * 64);
#pragma unroll
  for (int p = 0; p < 4; ++p) {
    int s = p * 16 + (t >> 4);
    int c = (t & 15) * 4;
    ushort4 v = *(const ushort4*)(src + (size_t)s * 64 + c);
    tile[s][c] = v.x; tile[s][c + 1] = v.y; tile[s][c + 2] = v.z; tile[s][c + 3] = v.w;
  }
  __syncthreads();
  ushort* dst = (ushort*)(Vt + ((size_t)bh * 64) * Sn + s0);
#pragma unroll
  for (int p = 0; p < 4; ++p) {
    int d = p * 16 + (t >> 4);
    int c = (t & 15) * 4;  // s offset within tile
    ushort4 v;
    v.x = tile[c][d]; v.y = tile[c + 1][d]; v.z = tile[c + 2][d]; v.w = tile[c + 3][d];
    *(ushort4*)(dst + (size_t)d * Sn + c) = v;
  }
}

// ---------------------------------------------------------------- GEMM core
// C = A[M][K] · Bt[N][K]^T. BMx128 tile (BM in {64,128}), BK=32, 256 threads
// (2x2 waves of (BM/2)x64). global_load_lds w16 staging; chunk XOR-swizzle.
template <int K_, int BM>
__device__ __forceinline__ void gemm_core(
    const bf16_t* __restrict__ A, const bf16_t* __restrict__ Bt,
    f32x4 (&acc)[BM / 32][4], int& col0, int& row0) {
  __shared__ bf16_t As[2][BM * 32];
  __shared__ bf16_t Bs[2][128 * 32];
  const int tid = threadIdx.x, lane = tid & 63, wid = tid >> 6;
  const int wm = wid >> 1, wn = wid & 1;
  const int m0 = blockIdx.y * BM, n0 = blockIdx.x * 128;
  const int KT = K_ / 32;
  constexpr int MI = BM / 32;

  auto stage = [&](bf16_t* as, bf16_t* bs, int kt) {
    int csw = ((lane & 3) ^ ((lane >> 2) & 3)) * 8;
#pragma unroll
    for (int j = 0; j < BM / 64; ++j) {
      int r0 = wid * (BM / 4) + j * 16;
      const bf16_t* ga = A + (size_t)(m0 + r0 + (lane >> 2)) * K_ + kt * 32 + csw;
      __builtin_amdgcn_global_load_lds((const AS1 void*)ga, (AS3 void*)(as + r0 * 32), 16, 0, 0);
    }
#pragma unroll
    for (int j = 0; j < 2; ++j) {
      int r0 = wid * 32 + j * 16;
      const bf16_t* gb = Bt + (size_t)(n0 + r0 + (lane >> 2)) * K_ + kt * 32 + csw;
      __builtin_amdgcn_global_load_lds((const AS1 void*)gb, (AS3 void*)(bs + r0 * 32), 16, 0, 0);
    }
  };
  auto compute = [&](const bf16_t* as, const bf16_t* bs) {
    bf16x8 af[MI], bfr[4];
    uint32_t swz = (uint32_t)(((lane >> 4) ^ (lane & 3)) << 4);
#pragma unroll
    for (int mi = 0; mi < MI; ++mi) {
      uint32_t row = (uint32_t)(wm * (BM / 2) + mi * 16 + (lane & 15));
      af[mi] = *(const bf16x8*)((const char*)as + row * 64 + swz);
    }
#pragma unroll
    for (int ni = 0; ni < 4; ++ni) {
      uint32_t row = (uint32_t)(wn * 64 + ni * 16 + (lane & 15));
      bfr[ni] = *(const bf16x8*)((const char*)bs + row * 64 + swz);
    }
#pragma unroll
    for (int mi = 0; mi < MI; ++mi)
#pragma unroll
      for (int ni = 0; ni < 4; ++ni)
        acc[mi][ni] = __builtin_amdgcn_mfma_f32_16x16x32_bf16(af[mi], bfr[ni], acc[mi][ni], 0, 0, 0);
  };

  stage(As[0], Bs[0], 0);
  __syncthreads();
  int cur = 0;
  for (int kt = 0; kt < KT - 1; ++kt) {
    stage(As[cur ^ 1], Bs[cur ^ 1], kt + 1);
    compute(As[cur], Bs[cur]);
    __syncthreads();
    cur ^= 1;
  }
  compute(As[cur], Bs[cur]);
  col0 = n0 + wn * 64 + (lane & 15);
  row0 = m0 + wm * (BM / 2) + ((lane >> 4) << 2);
}

__global__ __launch_bounds__(256) void gemm_qkv(
    const bf16_t* __restrict__ A, const bf16_t* __restrict__ Bt,
    const float* __restrict__ bias, bf16_t* __restrict__ Qb,
    bf16_t* __restrict__ Kb, bf16_t* __restrict__ Vb) {
  f32x4 acc[4][4] = {};
  int col0, row0;
  gemm_core<1024, 128>(A, Bt, acc, col0, row0);
#pragma unroll
  for (int ni = 0; ni < 4; ++ni) {
    int n = col0 + ni * 16;
    float bv = bias[n];
    int which = n >> 10, nn = n & 1023;
    int h = nn >> 6, dd = nn & 63;
    bf16_t* dst = which == 0 ? Qb : (which == 1 ? Kb : Vb);
    // Q: fold 1/sqrt(64) AND log2(e) (exp2-softmax) into the stored scale.
    float scl = which == 0 ? 0.125f * 1.44269504f : 1.0f;
#pragma unroll
    for (int mi = 0; mi < 4; ++mi)
#pragma unroll
      for (int i = 0; i < 4; ++i) {
        int m = row0 + mi * 16 + i;
        int b = m >> 11, s = m & 2047;
        float v = (acc[mi][ni][i] + bv) * scl;
        dst[(((size_t)b * Hn + h) * Sn + s) * 64 + dd] = (bf16_t)v;
      }
  }
}

__global__ __launch_bounds__(256) void gemm_out(
    const bf16_t* __restrict__ A, const bf16_t* __restrict__ Bt,
    const float* __restrict__ bias, float* __restrict__ out) {
  f32x4 acc[2][4] = {};
  int col0, row0;
  gemm_core<1024, 64>(A, Bt, acc, col0, row0);
#pragma unroll
  for (int ni = 0; ni < 4; ++ni) {
    int n = col0 + ni * 16;
    float bv = bias[n];
#pragma unroll
    for (int mi = 0; mi < 2; ++mi)
#pragma unroll
      for (int i = 0; i < 4; ++i) {
        int m = row0 + mi * 16 + i;
        out[(size_t)m * En + n] = acc[mi][ni][i] + bv;
      }
  }
}

// -------------------------------------------------------- flash attention fwd
// grid (32=bh, 32=y), 256 threads, 40KB LDS => 4 blocks/CU, ALL 1024 blocks
// co-resident (4 waves/SIMD doubles VALU slot fill vs R10's 2/CU).
// y -> q_tile balanced permutation: g=y&7, k=y>>3:
//   {k0: 31-g, k1: 16+g, k2: 15-g, k3: g}  -- each CU's 4 blocks (y, y+8,
// y+16, y+24 under round-robin) sum to 66 tile-iters (= pairing's balance),
// longest first; id%8 = bh%8 keeps per-XCD K/V working set 2MB < L2 (T1).
// Swapped-QK in-register softmax: S^T = mfma(K,Q), lane owns q=lane&15;
// P->bf16 cvt_pk; PV B-frag via ds_bpermute; O^T = mfma(Vt,P); LDS-transposed
// epilogue. exp2-softmax, defer-max thr 11.5, setprio (T5).
__global__ __launch_bounds__(256) void attn_fwd(
    const bf16_t* __restrict__ Qb, const bf16_t* __restrict__ Kb,
    const bf16_t* __restrict__ Vt, bf16_t* __restrict__ AO) {
  __shared__ bf16_t Ks[2][64 * 64];
  __shared__ bf16_t Vs[2][64 * 64];
  __shared__ bf16_t Ps[4][16 * 64];   // epilogue transpose only
  const int tid = threadIdx.x, lane = tid & 63, wid = tid >> 6;
  const int bh = blockIdx.x;
  const int y = blockIdx.y, gy = y & 7, ky = y >> 3;
  const int q_tile = ky == 0 ? 31 - gy : (ky == 1 ? 16 + gy : (ky == 2 ? 15 - gy : gy));
  const int nt = q_tile + 1;
  const int qb = q_tile * 64 + wid * 16;
  const int qmy = qb + (lane & 15);

  const int rl = lane >> 3;   // row within 8-row group
  const int cp = lane & 7;    // physical 16B chunk
  auto issueKV = [&](int buf, int t) {
#pragma unroll
    for (int j = 0; j < 2; ++j) {
      int r = wid * 16 + j * 8 + rl;
      int sc = cp ^ rl;       // source logical chunk (pre-swizzle, r&7==rl)
      const bf16_t* gk = Kb + (((size_t)bh * Sn + t * 64 + r) << 6) + (sc << 3);
      __builtin_amdgcn_global_load_lds((const AS1 void*)gk,
          (AS3 void*)(&Ks[buf][wid * 1024 + j * 512]), 16, 0, 0);
      const bf16_t* gv = Vt + ((size_t)bh * 64 + r) * Sn + t * 64 + (sc << 3);
      __builtin_amdgcn_global_load_lds((const AS1 void*)gv,
          (AS3 void*)(&Vs[buf][wid * 1024 + j * 512]), 16, 0, 0);
    }
  };

  // bpermute source indices for the P-fragment build (byte = lane*4):
  // srcA pulls from lane 32*(g&1) + q; srcB = srcA + 16 lanes.
  const int srcA = (((lane & 15) + ((lane & 16) << 1)) << 2);
  const int srcB = srcA + 64;
  const bool hi = lane >= 32;

  bf16x8 aq[2];
  {
    const bf16_t* qp = Qb + ((size_t)bh * Sn + qb + (lane & 15)) * 64 + ((lane >> 4) << 3);
    aq[0] = *(const bf16x8*)qp;
    aq[1] = *(const bf16x8*)(qp + 32);
  }
  f32x4 O[4] = {};
  float m_run = -1e30f, l_run = 0.f;

  int buf = 0;
  issueKV(0, 0);

  for (int t = 0; t < nt; ++t) {
    asm volatile("s_waitcnt vmcnt(0)" ::: "memory");
    __syncthreads();
    if (t + 1 < nt) issueKV(buf ^ 1, t + 1);
    const char* ksb = (const char*)Ks[buf];
    const char* vsb = (const char*)Vs[buf];
    // S^T = K · Q^T : lane holds S[kv = ni*16 + 4*(lane>>4)+i][q = lane&15]
    f32x4 sc[4];
    __builtin_amdgcn_s_setprio(1);
#pragma unroll
    for (int ni = 0; ni < 4; ++ni) {
      int kvr = ni * 16 + (lane & 15);
      uint32_t o0 = (uint32_t)(kvr * 128 + ((lane >> 4) << 4)) ^ (uint32_t)((kvr & 7) << 4);
      uint32_t o1 = (uint32_t)(kvr * 128 + 64 + ((lane >> 4) << 4)) ^ (uint32_t)((kvr & 7) << 4);
      bf16x8 b0 = *(const bf16x8*)(ksb + o0);
      bf16x8 b1 = *(const bf16x8*)(ksb + o1);
      f32x4 z = {};
      z = __builtin_amdgcn_mfma_f32_16x16x32_bf16(b0, aq[0], z, 0, 0, 0);
      sc[ni] = __builtin_amdgcn_mfma_f32_16x16x32_bf16(b1, aq[1], z, 0, 0, 0);
    }
    __builtin_amdgcn_s_setprio(0);
    if (t == nt - 1) {  // diagonal tile: causal mask (kv > q -> -inf)
#pragma unroll
      for (int ni = 0; ni < 4; ++ni) {
        int kvbase = t * 64 + ni * 16 + ((lane >> 4) << 2);
#pragma unroll
        for (int i = 0; i < 4; ++i)
          if (kvbase + i > qmy) sc[ni][i] = -1e30f;
      }
    }
    // tile max for q = lane&15: in-lane over 16, then across the 4 groups
    float mt = sc[0][0];
#pragma unroll
    for (int ni = 0; ni < 4; ++ni)
#pragma unroll
      for (int i = 0; i < 4; ++i) mt = fmaxf(mt, sc[ni][i]);
    mt = fmaxf(mt, __shfl_xor(mt, 16));
    mt = fmaxf(mt, __shfl_xor(mt, 32));
    // defer-max: rescale only when max grew by > 11.5 (log2 units)
    if (!__all(mt <= m_run + 11.5f)) {
      float mn = fmaxf(m_run, mt);
      float s = __builtin_exp2f(m_run - mn);
      m_run = mn;
      l_run *= s;
#pragma unroll
      for (int n2 = 0; n2 < 4; ++n2)
#pragma unroll
        for (int i = 0; i < 4; ++i) O[n2][i] *= s;
    }
    // P = exp2(S - m); pack to bf16 pairs
    float rs = 0.f;
    uint32_t pk[4][2];
#pragma unroll
    for (int ni = 0; ni < 4; ++ni) {
      float p0 = __builtin_exp2f(sc[ni][0] - m_run);
      float p1 = __builtin_exp2f(sc[ni][1] - m_run);
      float p2 = __builtin_exp2f(sc[ni][2] - m_run);
      float p3 = __builtin_exp2f(sc[ni][3] - m_run);
      rs += (p0 + p1) + (p2 + p3);
      pk[ni][0] = cvt_pk_bf16(p0, p1);
      pk[ni][1] = cvt_pk_bf16(p2, p3);
    }
    rs += __shfl_xor(rs, 16);
    rs += __shfl_xor(rs, 32);
    l_run += rs;
    // build PV B-fragment: W[t][w] = pk[2t+(g>>1)][w&1] from lane
    // 32*(g&1) + 16*(w>>1) + q   (verified mapping)
    union U8 { uint32_t u[4]; bf16x8 v; } pw0, pw1;
#pragma unroll
    for (int w = 0; w < 4; ++w) {
      int srci = (w < 2) ? srcA : srcB;
      uint32_t x0 = (uint32_t)__builtin_amdgcn_ds_bpermute(srci, (int)pk[0][w & 1]);
      uint32_t y0 = (uint32_t)__builtin_amdgcn_ds_bpermute(srci, (int)pk[1][w & 1]);
      pw0.u[w] = hi ? y0 : x0;
      uint32_t x1 = (uint32_t)__builtin_amdgcn_ds_bpermute(srci, (int)pk[2][w & 1]);
      uint32_t y1 = (uint32_t)__builtin_amdgcn_ds_bpermute(srci, (int)pk[3][w & 1]);
      pw1.u[w] = hi ? y1 : x1;
    }
    // O^T += V^T · P^T : lane holds O[q = lane&15][d = n2*16 + 4*(lane>>4)+i]
    __builtin_amdgcn_s_setprio(1);
#pragma unroll
    for (int n2 = 0; n2 < 4; ++n2) {
      int dr = n2 * 16 + (lane & 15);
      uint32_t o0 = (uint32_t)(dr * 128 + ((lane >> 4) << 4)) ^ (uint32_t)((dr & 7) << 4);
      uint32_t o1 = (uint32_t)(dr * 128 + 64 + ((lane >> 4) << 4)) ^ (uint32_t)((dr & 7) << 4);
      bf16x8 v0 = *(const bf16x8*)(vsb + o0);
      bf16x8 v1 = *(const bf16x8*)(vsb + o1);
      O[n2] = __builtin_amdgcn_mfma_f32_16x16x32_bf16(v0, pw0.v, O[n2], 0, 0, 0);
      O[n2] = __builtin_amdgcn_mfma_f32_16x16x32_bf16(v1, pw1.v, O[n2], 0, 0, 0);
    }
    __builtin_amdgcn_s_setprio(0);
    buf ^= 1;
  }
  // epilogue: O^T -> row-major via per-wave LDS (XOR-swizzled), then store
  char* pw = (char*)Ps[wid];
  const float inv = 1.0f / l_run;
  const int ql = lane & 15, g = lane >> 4;
#pragma unroll
  for (int n2 = 0; n2 < 4; ++n2)
#pragma unroll
    for (int p2 = 0; p2 < 2; ++p2) {
      uint32_t w = cvt_pk_bf16(O[n2][2 * p2] * inv, O[n2][2 * p2 + 1] * inv);
      uint32_t byte = (uint32_t)(ql * 128 + n2 * 32 + g * 8 + p2 * 4) ^ (uint32_t)((ql & 7) << 4);
      *(uint32_t*)(pw + byte) = w;
    }
  asm volatile("s_waitcnt lgkmcnt(0)" ::: "memory");
  __builtin_amdgcn_sched_barrier(0);
  int b = bh >> 4, h = bh & 15;
#pragma unroll
  for (int i = 0; i < 4; ++i) {
    int ql2 = (g << 2) + i;
    int qrow = qb + ql2;
#pragma unroll
    for (int n2 = 0; n2 < 4; ++n2) {
      int d = n2 * 16 + ql;
      uint32_t byte = (uint32_t)(ql2 * 128 + d * 2) ^ (uint32_t)((ql2 & 7) << 4);
      AO[((size_t)b * Sn + qrow) * En + h * 64 + d] = *(bf16_t*)(pw + byte);
    }
  }
}

// ---------------------------------------------------------------- launch
extern "C" void kernel_launch(void* const* d_in, const int* in_sizes, int n_in,
                              void* d_out, int out_size, void* d_ws, size_t ws_size,
                              hipStream_t stream) {
  const float* X     = (const float*)d_in[0];
  // d_in[1] = mask (causal; applied analytically)
  const float* W_qkv = (const float*)d_in[2];
  const float* b_qkv = (const float*)d_in[3];
  const float* W_o   = (const float*)d_in[4];
  const float* b_o   = (const float*)d_in[5];
  float* out = (float*)d_out;

  char* ws = (char*)d_ws;
  bf16_t* Xb  = (bf16_t*)(ws);
  bf16_t* WqT = (bf16_t*)(ws + 8388608);
  bf16_t* WoT = (bf16_t*)(ws + 14680064);
  bf16_t* Qb  = (bf16_t*)(ws + 16777216);
  bf16_t* Kb  = (bf16_t*)(ws + 25165824);
  bf16_t* Vb  = (bf16_t*)(ws + 33554432);
  bf16_t* Vt  = (bf16_t*)(ws + 41943040);
  bf16_t* AO  = (bf16_t*)(ws + 50331648);

  convert_f32_bf16<<<4096, 256, 0, stream>>>(X, Xb, Bn * Sn * En);
  transpose_conv<<<dim3(96, 32), 256, 0, stream>>>(W_qkv, WqT, 1024, 3072);
  transpose_conv<<<dim3(32, 32), 256, 0, stream>>>(W_o, WoT, 1024, 1024);
  gemm_qkv<<<dim3(24, 32), 256, 0, stream>>>(Xb, WqT, b_qkv, Qb, Kb, Vb);
  transpose_v<<<dim3(32, 32), 256, 0, stream>>>(Vb, Vt);
  attn_fwd<<<dim3(32, 32), 256, 0, stream>>>(Qb, Kb, Vt, AO);
  gemm_out<<<dim3(8, 64), 256, 0, stream>>>(AO, WoT, b_o, out);
}